// Round 2
// baseline (419.869 us; speedup 1.0000x reference)
//
#include <hip/hip_runtime.h>
#include <hip/hip_bf16.h>

#define N_NODES 100000
#define N_EDGES 1600000
#define NEG_SLOPE 0.2f
#define LN_EPS 1e-5f

// ---------------- GEMM: h = x @ W  (fp32, 128x128 tile, 8x8/thread) ----------------
// Fused epilogue: a_src[n][head] = dot(h[n, head*16 : head*16+16], att_src[head])
// computed from the accumulator registers (saves re-reading all of h).
__global__ __launch_bounds__(256) void gemm_kernel(const float* __restrict__ x,
                                                   const float* __restrict__ W,
                                                   const float* __restrict__ att_src,
                                                   float* __restrict__ h,
                                                   float* __restrict__ a_srcp) {
    __shared__ float xs[128 * 64];   // [r][k]  32 KB
    __shared__ float ws[64 * 128];   // [k][c]  32 KB
    const int t = threadIdx.x;
    const int nbase = blockIdx.x * 128;
    const int cx = (t & 15) * 8;     // 8 consecutive output cols
    const int ry = (t >> 4) * 8;     // 8 consecutive output rows
    float acc[8][8] = {};
    for (int kb = 0; kb < 2; ++kb) {
        __syncthreads();
        // stage x half-tile: 2048 float4s
        for (int i = t; i < 2048; i += 256) {
            int r = i >> 4, kq = i & 15;
            int gr = nbase + r;
            gr = gr < N_NODES ? gr : N_NODES - 1;
            *reinterpret_cast<float4*>(&xs[r * 64 + kq * 4]) =
                *reinterpret_cast<const float4*>(&x[(size_t)gr * 128 + kb * 64 + kq * 4]);
        }
        // stage W half-tile
        for (int i = t; i < 2048; i += 256) {
            int k = i >> 5, cq = i & 31;
            *reinterpret_cast<float4*>(&ws[k * 128 + cq * 4]) =
                *reinterpret_cast<const float4*>(&W[(size_t)(kb * 64 + k) * 128 + cq * 4]);
        }
        __syncthreads();
        for (int kq = 0; kq < 16; ++kq) {
            float4 xv[8];
            float4 wv[4][2];
#pragma unroll
            for (int r = 0; r < 8; ++r)
                xv[r] = *reinterpret_cast<const float4*>(&xs[(ry + r) * 64 + kq * 4]);
#pragma unroll
            for (int k2 = 0; k2 < 4; ++k2) {
                wv[k2][0] = *reinterpret_cast<const float4*>(&ws[(kq * 4 + k2) * 128 + cx]);
                wv[k2][1] = *reinterpret_cast<const float4*>(&ws[(kq * 4 + k2) * 128 + cx + 4]);
            }
#pragma unroll
            for (int r = 0; r < 8; ++r) {
                const float* xf = reinterpret_cast<const float*>(&xv[r]);
#pragma unroll
                for (int k2 = 0; k2 < 4; ++k2) {
                    const float xx = xf[k2];
                    const float* w0 = reinterpret_cast<const float*>(&wv[k2][0]);
                    const float* w1 = reinterpret_cast<const float*>(&wv[k2][1]);
#pragma unroll
                    for (int c = 0; c < 4; ++c) {
                        acc[r][c] = fmaf(xx, w0[c], acc[r][c]);
                        acc[r][c + 4] = fmaf(xx, w1[c], acc[r][c + 4]);
                    }
                }
            }
        }
    }
#pragma unroll
    for (int r = 0; r < 8; ++r) {
        int gr = nbase + ry + r;
        if (gr < N_NODES) {
            *reinterpret_cast<float4*>(&h[(size_t)gr * 128 + cx]) =
                make_float4(acc[r][0], acc[r][1], acc[r][2], acc[r][3]);
            *reinterpret_cast<float4*>(&h[(size_t)gr * 128 + cx + 4]) =
                make_float4(acc[r][4], acc[r][5], acc[r][6], acc[r][7]);
        }
    }

    // ---- fused a_src epilogue: reuse xs as [128 rows][16 col-group slots] ----
    float asv[8];
#pragma unroll
    for (int c = 0; c < 8; ++c) asv[c] = att_src[cx + c];
    __syncthreads();   // everyone done reading xs/ws in the main loop
#pragma unroll
    for (int r = 0; r < 8; ++r) {
        float p = 0.f;
#pragma unroll
        for (int c = 0; c < 8; ++c) p += acc[r][c] * asv[c];
        xs[(ry + r) * 16 + (t & 15)] = p;
    }
    __syncthreads();
    // pair-reduce the two 8-col slots of each head; 1024 (row,head) entries
    for (int idx = t; idx < 1024; idx += 256) {
        int row = idx >> 3, hd = idx & 7;
        int gr = nbase + row;
        if (gr < N_NODES)
            a_srcp[gr * 8 + hd] = xs[row * 16 + hd * 2] + xs[row * 16 + hd * 2 + 1];
    }
}

// ---------------- degree count ----------------
__global__ __launch_bounds__(256) void deg_kernel(const int* __restrict__ ei, int* __restrict__ deg) {
    int i = blockIdx.x * 256 + threadIdx.x;
    if (i < N_EDGES) atomicAdd(&deg[ei[N_EDGES + i]], 1);
}

// ---------------- exclusive scan (3 kernels) ----------------
__global__ __launch_bounds__(256) void scan1_kernel(const int* __restrict__ deg,
                                                    int* __restrict__ rowptr,
                                                    int* __restrict__ blocksum) {
    __shared__ int sdata[256];
    const int t = threadIdx.x;
    const int gbase = blockIdx.x * 1024 + t * 4;
    int v[4];
#pragma unroll
    for (int j = 0; j < 4; ++j) v[j] = (gbase + j < N_NODES) ? deg[gbase + j] : 0;
    int tot = v[0] + v[1] + v[2] + v[3];
    sdata[t] = tot;
    __syncthreads();
    for (int off = 1; off < 256; off <<= 1) {
        int u = (t >= off) ? sdata[t - off] : 0;
        __syncthreads();
        sdata[t] += u;
        __syncthreads();
    }
    int excl = sdata[t] - tot;
    int run = excl;
#pragma unroll
    for (int j = 0; j < 4; ++j) {
        if (gbase + j < N_NODES) rowptr[gbase + j] = run;
        run += v[j];
    }
    if (t == 255) blocksum[blockIdx.x] = sdata[255];
}

__global__ __launch_bounds__(128) void scan2_kernel(int* __restrict__ blocksum, int nblocks) {
    __shared__ int sdata[128];
    const int t = threadIdx.x;
    int v = (t < nblocks) ? blocksum[t] : 0;
    sdata[t] = v;
    __syncthreads();
    for (int off = 1; off < 128; off <<= 1) {
        int u = (t >= off) ? sdata[t - off] : 0;
        __syncthreads();
        sdata[t] += u;
        __syncthreads();
    }
    if (t < nblocks) blocksum[t] = sdata[t] - v;   // exclusive
}

__global__ __launch_bounds__(256) void scan3_kernel(int* __restrict__ rowptr,
                                                    int* __restrict__ cursor,
                                                    const int* __restrict__ blocksum) {
    const int t = threadIdx.x;
    const int gbase = blockIdx.x * 1024 + t * 4;
    int off = blocksum[blockIdx.x];
#pragma unroll
    for (int j = 0; j < 4; ++j) {
        int i = gbase + j;
        if (i < N_NODES) {
            int val = rowptr[i] + off;
            rowptr[i] = val;
            cursor[i] = val;
        }
    }
    if (blockIdx.x == 0 && t == 0) rowptr[N_NODES] = N_EDGES;
}

// ---------------- scatter edges into CSR ----------------
__global__ __launch_bounds__(256) void scatter_kernel(const int* __restrict__ ei,
                                                      int* __restrict__ cursor,
                                                      int* __restrict__ csr_src) {
    int i = blockIdx.x * 256 + threadIdx.x;
    if (i >= N_EDGES) return;
    int src = ei[i];
    int dst = ei[N_EDGES + i];
    int pos = atomicAdd(&cursor[dst], 1);
    csr_src[pos] = src;
}

// ---------------- fused per-node aggregate + softmax + LN ----------------
// one 64-lane wave per node, split into two 32-lane halves.
// half = lane>>5 processes edges beg+half, beg+half+2, ... (unrolled x2, prefetch 1 iter ahead
// -> 4 independent h-row gathers in flight per wave)
// lane-within-half hl owns channels 4*hl .. 4*hl+3 (float4 gathers); head = hl>>2
__global__ __launch_bounds__(256) void node_aggregate_kernel(const int* __restrict__ rowptr,
                                                             const int* __restrict__ csr_src,
                                                             const float* __restrict__ h,
                                                             const float* __restrict__ a_srcp,
                                                             const float* __restrict__ x,
                                                             const float* __restrict__ att_dst,
                                                             const float* __restrict__ bias,
                                                             const float* __restrict__ gamma,
                                                             const float* __restrict__ beta,
                                                             float* __restrict__ out) {
    int node = blockIdx.x * 4 + (threadIdx.x >> 6);
    if (node >= N_NODES) return;
    const int lane = threadIdx.x & 63;
    const int half = lane >> 5;        // which 32-lane half
    const int hl = lane & 31;          // lane within half
    const int ch = hl * 4;             // 4 channels per lane
    const int head = hl >> 2;          // 4 lanes per head

    // a_dst for this node's head: 4-lane-group reduce (prologue only)
    float4 adv = *reinterpret_cast<const float4*>(att_dst + ch);
    float4 hn = *reinterpret_cast<const float4*>(h + (size_t)node * 128 + ch);
    float pd = hn.x * adv.x + hn.y * adv.y + hn.z * adv.z + hn.w * adv.w;
    pd += __shfl_xor(pd, 1);
    pd += __shfl_xor(pd, 2);
    const float adst = pd;

    const int beg = rowptr[node];
    const int end = rowptr[node + 1];

    float s = 0.f, acc0 = 0.f, acc1 = 0.f, acc2 = 0.f, acc3 = 0.f;

    const float4* __restrict__ hp = reinterpret_cast<const float4*>(h);

    int i = beg + half;
    if (i < end) {
        const int sF = csr_src[i];                 // fallback (clamp) index
        int s1i = (i + 2 < end) ? csr_src[i + 2] : sF;
        float4 h0 = hp[(size_t)sF * 32 + hl];
        float  a0 = a_srcp[sF * 8 + head];
        float4 h1 = hp[(size_t)s1i * 32 + hl];
        float  a1 = a_srcp[s1i * 8 + head];
        while (true) {
            // prefetch the next unroll pair (edges i+4, i+6)
            const int i4 = i + 4, i6 = i + 6;
            const int sN0 = (i4 < end) ? csr_src[i4] : sF;
            const int sN1 = (i6 < end) ? csr_src[i6] : sF;
            float4 hn0 = hp[(size_t)sN0 * 32 + hl];
            float  an0 = a_srcp[sN0 * 8 + head];
            float4 hn1 = hp[(size_t)sN1 * 32 + hl];
            float  an1 = a_srcp[sN1 * 8 + head];

            // edge i (always valid inside the loop)
            float e0 = a0 + adst;
            e0 = e0 >= 0.f ? e0 : NEG_SLOPE * e0;
            e0 = fminf(e0, 80.f);
            const float p0 = __expf(e0);
            s += p0;
            acc0 = fmaf(p0, h0.x, acc0);
            acc1 = fmaf(p0, h0.y, acc1);
            acc2 = fmaf(p0, h0.z, acc2);
            acc3 = fmaf(p0, h0.w, acc3);

            // edge i+2 (if valid)
            if (i + 2 < end) {
                float e1 = a1 + adst;
                e1 = e1 >= 0.f ? e1 : NEG_SLOPE * e1;
                e1 = fminf(e1, 80.f);
                const float p1 = __expf(e1);
                s += p1;
                acc0 = fmaf(p1, h1.x, acc0);
                acc1 = fmaf(p1, h1.y, acc1);
                acc2 = fmaf(p1, h1.z, acc2);
                acc3 = fmaf(p1, h1.w, acc3);
            }

            i += 4;
            if (i >= end) break;
            h0 = hn0; a0 = an0;
            h1 = hn1; a1 = an1;
        }
    }

    // combine the two halves (each channel now duplicated across halves)
    s += __shfl_xor(s, 32);
    acc0 += __shfl_xor(acc0, 32);
    acc1 += __shfl_xor(acc1, 32);
    acc2 += __shfl_xor(acc2, 32);
    acc3 += __shfl_xor(acc3, 32);

    // normalize + bias + residual (x is touch-once: non-temporal)
    const float rs = 1.0f / (s + 1e-16f);
    const float* xrp = x + (size_t)node * 128 + ch;
    float4 xr;
    xr.x = __builtin_nontemporal_load(xrp + 0);
    xr.y = __builtin_nontemporal_load(xrp + 1);
    xr.z = __builtin_nontemporal_load(xrp + 2);
    xr.w = __builtin_nontemporal_load(xrp + 3);
    float4 bv = *reinterpret_cast<const float4*>(bias + ch);
    float v0 = acc0 * rs + bv.x + xr.x;
    float v1 = acc1 * rs + bv.y + xr.y;
    float v2 = acc2 * rs + bv.z + xr.z;
    float v3 = acc3 * rs + bv.w + xr.w;

    // LayerNorm over 128 channels (full-wave reduce; every channel counted twice)
    float sum = v0 + v1 + v2 + v3;
    float sq = v0 * v0 + v1 * v1 + v2 * v2 + v3 * v3;
#pragma unroll
    for (int off = 32; off > 0; off >>= 1) {
        sum += __shfl_xor(sum, off);
        sq += __shfl_xor(sq, off);
    }
    const float mu = sum * (1.0f / 256.0f);
    const float var = sq * (1.0f / 256.0f) - mu * mu;
    const float inv = rsqrtf(var + LN_EPS);
    float4 gv = *reinterpret_cast<const float4*>(gamma + ch);
    float4 be = *reinterpret_cast<const float4*>(beta + ch);
    float o0 = (v0 - mu) * inv * gv.x + be.x;
    float o1 = (v1 - mu) * inv * gv.y + be.y;
    float o2 = (v2 - mu) * inv * gv.z + be.z;
    float o3 = (v3 - mu) * inv * gv.w + be.w;
    o0 = o0 > 0.f ? o0 : 0.f;
    o1 = o1 > 0.f ? o1 : 0.f;
    o2 = o2 > 0.f ? o2 : 0.f;
    o3 = o3 > 0.f ? o3 : 0.f;
    if (half == 0) {
        float* op = out + (size_t)node * 128 + ch;
        __builtin_nontemporal_store(o0, op + 0);
        __builtin_nontemporal_store(o1, op + 1);
        __builtin_nontemporal_store(o2, op + 2);
        __builtin_nontemporal_store(o3, op + 3);
    }
}

extern "C" void kernel_launch(void* const* d_in, const int* in_sizes, int n_in,
                              void* d_out, int out_size, void* d_ws, size_t ws_size,
                              hipStream_t stream) {
    const float* x = (const float*)d_in[0];
    const int* ei = (const int*)d_in[1];
    const float* W = (const float*)d_in[2];
    const float* att_src = (const float*)d_in[3];
    const float* att_dst = (const float*)d_in[4];
    const float* bias = (const float*)d_in[5];
    const float* gamma = (const float*)d_in[6];
    const float* beta = (const float*)d_in[7];
    float* out = (float*)d_out;

    char* base = (char*)d_ws;
    float* h      = (float*)base;                       // 51.2 MB
    float* a_srcp = (float*)(base + 51200000);          // 3.2 MB
    int* csr_src  = (int*)(base + 54400000);            // 6.4 MB
    int* rowptr   = (int*)(base + 60800000);            // 400,004 B
    int* cursor   = (int*)(base + 61200128);            // 400,004 B (also deg)
    int* blocksum = (int*)(base + 61600256);            // 512 B

    const int nscan = (N_NODES + 1023) / 1024;          // 98

    hipMemsetAsync(cursor, 0, (N_NODES) * sizeof(int), stream);   // deg = 0
    gemm_kernel<<<(N_NODES + 127) / 128, 256, 0, stream>>>(x, W, att_src, h, a_srcp);
    deg_kernel<<<(N_EDGES + 255) / 256, 256, 0, stream>>>(ei, cursor);
    scan1_kernel<<<nscan, 256, 0, stream>>>(cursor, rowptr, blocksum);
    scan2_kernel<<<1, 128, 0, stream>>>(blocksum, nscan);
    scan3_kernel<<<nscan, 256, 0, stream>>>(rowptr, cursor, blocksum);
    scatter_kernel<<<(N_EDGES + 255) / 256, 256, 0, stream>>>(ei, cursor, csr_src);
    node_aggregate_kernel<<<(N_NODES + 3) / 4, 256, 0, stream>>>(
        rowptr, csr_src, h, a_srcp, x, att_dst, bias, gamma, beta, out);
}

// Round 3
// 349.699 us; speedup vs baseline: 1.2007x; 1.2007x over previous
//
#include <hip/hip_runtime.h>
#include <hip/hip_fp16.h>

#define N_NODES 100000
#define N_EDGES 1600000
#define NEG_SLOPE 0.2f
#define LN_EPS 1e-5f

// ---------------- GEMM: h16 = fp16(x @ W)  (fp32 accum, 128x128 tile, 8x8/thread) ----
// Fused epilogue: a_src[n][head], a_dst[n][head] computed from fp32 accumulators.
// fp32 h is never materialized.
__global__ __launch_bounds__(256) void gemm_kernel(const float* __restrict__ x,
                                                   const float* __restrict__ W,
                                                   const float* __restrict__ att_src,
                                                   const float* __restrict__ att_dst,
                                                   __half* __restrict__ h16,
                                                   float* __restrict__ a_srcp,
                                                   float* __restrict__ a_dstp) {
    __shared__ float xs[128 * 64];   // [r][k]  32 KB (reused by epilogue)
    __shared__ float ws[64 * 128];   // [k][c]  32 KB
    const int t = threadIdx.x;
    const int nbase = blockIdx.x * 128;
    const int cx = (t & 15) * 8;     // 8 consecutive output cols
    const int ry = (t >> 4) * 8;     // 8 consecutive output rows
    float acc[8][8] = {};
    for (int kb = 0; kb < 2; ++kb) {
        __syncthreads();
        // stage x half-tile: 2048 float4s
        for (int i = t; i < 2048; i += 256) {
            int r = i >> 4, kq = i & 15;
            int gr = nbase + r;
            gr = gr < N_NODES ? gr : N_NODES - 1;
            *reinterpret_cast<float4*>(&xs[r * 64 + kq * 4]) =
                *reinterpret_cast<const float4*>(&x[(size_t)gr * 128 + kb * 64 + kq * 4]);
        }
        // stage W half-tile
        for (int i = t; i < 2048; i += 256) {
            int k = i >> 5, cq = i & 31;
            *reinterpret_cast<float4*>(&ws[k * 128 + cq * 4]) =
                *reinterpret_cast<const float4*>(&W[(size_t)(kb * 64 + k) * 128 + cq * 4]);
        }
        __syncthreads();
        for (int kq = 0; kq < 16; ++kq) {
            float4 xv[8];
            float4 wv[4][2];
#pragma unroll
            for (int r = 0; r < 8; ++r)
                xv[r] = *reinterpret_cast<const float4*>(&xs[(ry + r) * 64 + kq * 4]);
#pragma unroll
            for (int k2 = 0; k2 < 4; ++k2) {
                wv[k2][0] = *reinterpret_cast<const float4*>(&ws[(kq * 4 + k2) * 128 + cx]);
                wv[k2][1] = *reinterpret_cast<const float4*>(&ws[(kq * 4 + k2) * 128 + cx + 4]);
            }
#pragma unroll
            for (int r = 0; r < 8; ++r) {
                const float* xf = reinterpret_cast<const float*>(&xv[r]);
#pragma unroll
                for (int k2 = 0; k2 < 4; ++k2) {
                    const float xx = xf[k2];
                    const float* w0 = reinterpret_cast<const float*>(&wv[k2][0]);
                    const float* w1 = reinterpret_cast<const float*>(&wv[k2][1]);
#pragma unroll
                    for (int c = 0; c < 4; ++c) {
                        acc[r][c] = fmaf(xx, w0[c], acc[r][c]);
                        acc[r][c + 4] = fmaf(xx, w1[c], acc[r][c + 4]);
                    }
                }
            }
        }
    }
    // ---- h16 write (fp16, one 16B store per row per thread) ----
#pragma unroll
    for (int r = 0; r < 8; ++r) {
        int gr = nbase + ry + r;
        if (gr < N_NODES) {
            __half hb[8];
#pragma unroll
            for (int c = 0; c < 8; ++c) hb[c] = __float2half_rn(acc[r][c]);
            *reinterpret_cast<uint4*>(&h16[(size_t)gr * 128 + cx]) =
                *reinterpret_cast<const uint4*>(hb);
        }
    }

    // ---- fused a_src / a_dst epilogue from fp32 accumulators ----
    // xs reused: [0..2047] = src partials [128 rows][16 col-groups],
    //            [2048..4095] = dst partials
    float asv[8], adv[8];
#pragma unroll
    for (int c = 0; c < 8; ++c) {
        asv[c] = att_src[cx + c];
        adv[c] = att_dst[cx + c];
    }
    __syncthreads();   // everyone done reading xs/ws in the main loop
#pragma unroll
    for (int r = 0; r < 8; ++r) {
        float ps = 0.f, pd = 0.f;
#pragma unroll
        for (int c = 0; c < 8; ++c) {
            ps = fmaf(acc[r][c], asv[c], ps);
            pd = fmaf(acc[r][c], adv[c], pd);
        }
        xs[(ry + r) * 16 + (t & 15)] = ps;
        xs[2048 + (ry + r) * 16 + (t & 15)] = pd;
    }
    __syncthreads();
    // pair-reduce the two 8-col slots of each head; 1024 (row,head) entries
    for (int idx = t; idx < 1024; idx += 256) {
        int row = idx >> 3, hd = idx & 7;
        int gr = nbase + row;
        if (gr < N_NODES) {
            a_srcp[gr * 8 + hd] = xs[row * 16 + hd * 2] + xs[row * 16 + hd * 2 + 1];
            a_dstp[gr * 8 + hd] = xs[2048 + row * 16 + hd * 2] + xs[2048 + row * 16 + hd * 2 + 1];
        }
    }
}

// ---------------- degree count ----------------
__global__ __launch_bounds__(256) void deg_kernel(const int* __restrict__ ei, int* __restrict__ deg) {
    int i = blockIdx.x * 256 + threadIdx.x;
    if (i < N_EDGES) atomicAdd(&deg[ei[N_EDGES + i]], 1);
}

// ---------------- exclusive scan (3 kernels) ----------------
__global__ __launch_bounds__(256) void scan1_kernel(const int* __restrict__ deg,
                                                    int* __restrict__ rowptr,
                                                    int* __restrict__ blocksum) {
    __shared__ int sdata[256];
    const int t = threadIdx.x;
    const int gbase = blockIdx.x * 1024 + t * 4;
    int v[4];
#pragma unroll
    for (int j = 0; j < 4; ++j) v[j] = (gbase + j < N_NODES) ? deg[gbase + j] : 0;
    int tot = v[0] + v[1] + v[2] + v[3];
    sdata[t] = tot;
    __syncthreads();
    for (int off = 1; off < 256; off <<= 1) {
        int u = (t >= off) ? sdata[t - off] : 0;
        __syncthreads();
        sdata[t] += u;
        __syncthreads();
    }
    int excl = sdata[t] - tot;
    int run = excl;
#pragma unroll
    for (int j = 0; j < 4; ++j) {
        if (gbase + j < N_NODES) rowptr[gbase + j] = run;
        run += v[j];
    }
    if (t == 255) blocksum[blockIdx.x] = sdata[255];
}

__global__ __launch_bounds__(128) void scan2_kernel(int* __restrict__ blocksum, int nblocks) {
    __shared__ int sdata[128];
    const int t = threadIdx.x;
    int v = (t < nblocks) ? blocksum[t] : 0;
    sdata[t] = v;
    __syncthreads();
    for (int off = 1; off < 128; off <<= 1) {
        int u = (t >= off) ? sdata[t - off] : 0;
        __syncthreads();
        sdata[t] += u;
        __syncthreads();
    }
    if (t < nblocks) blocksum[t] = sdata[t] - v;   // exclusive
}

__global__ __launch_bounds__(256) void scan3_kernel(int* __restrict__ rowptr,
                                                    int* __restrict__ cursor,
                                                    const int* __restrict__ blocksum) {
    const int t = threadIdx.x;
    const int gbase = blockIdx.x * 1024 + t * 4;
    int off = blocksum[blockIdx.x];
#pragma unroll
    for (int j = 0; j < 4; ++j) {
        int i = gbase + j;
        if (i < N_NODES) {
            int val = rowptr[i] + off;
            rowptr[i] = val;
            cursor[i] = val;
        }
    }
    if (blockIdx.x == 0 && t == 0) rowptr[N_NODES] = N_EDGES;
}

// ---------------- scatter edges into CSR ----------------
__global__ __launch_bounds__(256) void scatter_kernel(const int* __restrict__ ei,
                                                      int* __restrict__ cursor,
                                                      int* __restrict__ csr_src) {
    int i = blockIdx.x * 256 + threadIdx.x;
    if (i >= N_EDGES) return;
    int src = ei[i];
    int dst = ei[N_EDGES + i];
    int pos = atomicAdd(&cursor[dst], 1);
    csr_src[pos] = src;
}

// ---------------- fused per-node aggregate + softmax + LN ----------------
// one 64-lane wave per node, split into four 16-lane quarters.
// quarter q processes edges beg+q, beg+q+4, ... (single prefetch -> ~8 gathers
// in flight per wave). lane-within-quarter ql owns channels 8*ql .. 8*ql+7
// (one uint4 = 8 fp16 per edge); head = ql>>1. 256B coalesced gather per edge.
__global__ __launch_bounds__(256) void node_aggregate_kernel(const int* __restrict__ rowptr,
                                                             const int* __restrict__ csr_src,
                                                             const __half* __restrict__ h16,
                                                             const float* __restrict__ a_srcp,
                                                             const float* __restrict__ a_dstp,
                                                             const float* __restrict__ x,
                                                             const float* __restrict__ bias,
                                                             const float* __restrict__ gamma,
                                                             const float* __restrict__ beta,
                                                             float* __restrict__ out) {
    int node = blockIdx.x * 4 + (threadIdx.x >> 6);
    if (node >= N_NODES) return;
    const int lane = threadIdx.x & 63;
    const int q = lane >> 4;           // quarter 0..3
    const int ql = lane & 15;          // lane within quarter
    const int ch = ql * 8;             // 8 channels per lane
    const int head = ql >> 1;          // 2 lanes per head

    const float adst = a_dstp[node * 8 + head];

    const int beg = rowptr[node];
    const int end = rowptr[node + 1];

    float s = 0.f;
    float accv[8] = {};

    const uint4* __restrict__ hp = reinterpret_cast<const uint4*>(h16);  // row = 16 uint4

    int i = beg + q;
    if (i < end) {
        const int sF = csr_src[i];                  // fallback (clamp) index
        int s1 = (i + 4 < end) ? csr_src[i + 4] : sF;
        uint4 hv = hp[(size_t)sF * 16 + ql];
        float as = a_srcp[sF * 8 + head];
        while (true) {
            const uint4 hc = hv;
            const float ac = as;
            const int sN = s1;
            const int i8 = i + 8;
            s1 = (i8 < end) ? csr_src[i8] : sF;      // index 2 iterations ahead
            hv = hp[(size_t)sN * 16 + ql];           // gather 1 iteration ahead
            as = a_srcp[sN * 8 + head];

            float e = ac + adst;
            e = e >= 0.f ? e : NEG_SLOPE * e;
            e = fminf(e, 80.f);                      // overflow insurance (no-op here)
            const float p = __expf(e);
            s += p;
            const __half2* hh = reinterpret_cast<const __half2*>(&hc);
#pragma unroll
            for (int j = 0; j < 4; ++j) {
                const float2 f = __half22float2(hh[j]);
                accv[2 * j] = fmaf(p, f.x, accv[2 * j]);
                accv[2 * j + 1] = fmaf(p, f.y, accv[2 * j + 1]);
            }

            i += 4;
            if (i >= end) break;
        }
    }

    // combine the four quarters (each channel now present in all quarters)
    s += __shfl_xor(s, 16);
    s += __shfl_xor(s, 32);
#pragma unroll
    for (int j = 0; j < 8; ++j) {
        accv[j] += __shfl_xor(accv[j], 16);
        accv[j] += __shfl_xor(accv[j], 32);
    }

    // normalize + bias + residual (x is touch-once: non-temporal)
    const float rs = 1.0f / (s + 1e-16f);
    const float* xrp = x + (size_t)node * 128 + ch;
    float v[8];
#pragma unroll
    for (int j = 0; j < 8; ++j) {
        const float xr = __builtin_nontemporal_load(xrp + j);
        v[j] = accv[j] * rs + bias[ch + j] + xr;
    }

    // LayerNorm over 128 channels (full-wave reduce; every channel counted 4x)
    float sum = 0.f, sq = 0.f;
#pragma unroll
    for (int j = 0; j < 8; ++j) {
        sum += v[j];
        sq = fmaf(v[j], v[j], sq);
    }
#pragma unroll
    for (int off = 32; off > 0; off >>= 1) {
        sum += __shfl_xor(sum, off);
        sq += __shfl_xor(sq, off);
    }
    const float mu = sum * (1.0f / 512.0f);
    const float var = sq * (1.0f / 512.0f) - mu * mu;
    const float inv = rsqrtf(var + LN_EPS);
    if (q == 0) {
        float o[8];
#pragma unroll
        for (int j = 0; j < 8; ++j) {
            float t = (v[j] - mu) * inv * gamma[ch + j] + beta[ch + j];
            o[j] = t > 0.f ? t : 0.f;
        }
        float* op = out + (size_t)node * 128 + ch;
#pragma unroll
        for (int j = 0; j < 8; ++j) __builtin_nontemporal_store(o[j], op + j);
    }
}

extern "C" void kernel_launch(void* const* d_in, const int* in_sizes, int n_in,
                              void* d_out, int out_size, void* d_ws, size_t ws_size,
                              hipStream_t stream) {
    const float* x = (const float*)d_in[0];
    const int* ei = (const int*)d_in[1];
    const float* W = (const float*)d_in[2];
    const float* att_src = (const float*)d_in[3];
    const float* att_dst = (const float*)d_in[4];
    const float* bias = (const float*)d_in[5];
    const float* gamma = (const float*)d_in[6];
    const float* beta = (const float*)d_in[7];
    float* out = (float*)d_out;

    char* base = (char*)d_ws;
    __half* h16   = (__half*)base;                      // 25.6 MB
    float* a_srcp = (float*)(base + 25600000);          // 3.2 MB
    float* a_dstp = (float*)(base + 28800000);          // 3.2 MB
    int* csr_src  = (int*)(base + 32000000);            // 6.4 MB
    int* rowptr   = (int*)(base + 38400000);            // 400,004 B
    int* cursor   = (int*)(base + 38800128);            // 400,004 B (also deg)
    int* blocksum = (int*)(base + 39200256);            // 512 B

    const int nscan = (N_NODES + 1023) / 1024;          // 98

    hipMemsetAsync(cursor, 0, (N_NODES) * sizeof(int), stream);   // deg = 0
    gemm_kernel<<<(N_NODES + 127) / 128, 256, 0, stream>>>(x, W, att_src, att_dst,
                                                           h16, a_srcp, a_dstp);
    deg_kernel<<<(N_EDGES + 255) / 256, 256, 0, stream>>>(ei, cursor);
    scan1_kernel<<<nscan, 256, 0, stream>>>(cursor, rowptr, blocksum);
    scan2_kernel<<<1, 128, 0, stream>>>(blocksum, nscan);
    scan3_kernel<<<nscan, 256, 0, stream>>>(rowptr, cursor, blocksum);
    scatter_kernel<<<(N_EDGES + 255) / 256, 256, 0, stream>>>(ei, cursor, csr_src);
    node_aggregate_kernel<<<(N_NODES + 3) / 4, 256, 0, stream>>>(
        rowptr, csr_src, h16, a_srcp, a_dstp, x, bias, gamma, beta, out);
}

// Round 4
// 201.997 us; speedup vs baseline: 2.0786x; 1.7312x over previous
//
#include <hip/hip_runtime.h>
#include <hip/hip_fp16.h>

#define N_NODES 100000
#define N_EDGES 1600000
#define NEG_SLOPE 0.2f
#define LN_EPS 1e-5f
#define NB 782            // ceil(N_NODES / 128) buckets, bucket = dst >> 7

// ---------------- GEMM: h16 = fp16(x @ W)  (fp32 accum, 128x128 tile, 8x8/thread) ----
// Fused epilogue: a_src[n][head], a_dst[n][head] computed from fp32 accumulators.
__global__ __launch_bounds__(256) void gemm_kernel(const float* __restrict__ x,
                                                   const float* __restrict__ W,
                                                   const float* __restrict__ att_src,
                                                   const float* __restrict__ att_dst,
                                                   __half* __restrict__ h16,
                                                   float* __restrict__ a_srcp,
                                                   float* __restrict__ a_dstp) {
    __shared__ float xs[128 * 64];   // [r][k]  32 KB (reused by epilogue)
    __shared__ float ws[64 * 128];   // [k][c]  32 KB
    const int t = threadIdx.x;
    const int nbase = blockIdx.x * 128;
    const int cx = (t & 15) * 8;     // 8 consecutive output cols
    const int ry = (t >> 4) * 8;     // 8 consecutive output rows
    float acc[8][8] = {};
    for (int kb = 0; kb < 2; ++kb) {
        __syncthreads();
        for (int i = t; i < 2048; i += 256) {
            int r = i >> 4, kq = i & 15;
            int gr = nbase + r;
            gr = gr < N_NODES ? gr : N_NODES - 1;
            *reinterpret_cast<float4*>(&xs[r * 64 + kq * 4]) =
                *reinterpret_cast<const float4*>(&x[(size_t)gr * 128 + kb * 64 + kq * 4]);
        }
        for (int i = t; i < 2048; i += 256) {
            int k = i >> 5, cq = i & 31;
            *reinterpret_cast<float4*>(&ws[k * 128 + cq * 4]) =
                *reinterpret_cast<const float4*>(&W[(size_t)(kb * 64 + k) * 128 + cq * 4]);
        }
        __syncthreads();
        for (int kq = 0; kq < 16; ++kq) {
            float4 xv[8];
            float4 wv[4][2];
#pragma unroll
            for (int r = 0; r < 8; ++r)
                xv[r] = *reinterpret_cast<const float4*>(&xs[(ry + r) * 64 + kq * 4]);
#pragma unroll
            for (int k2 = 0; k2 < 4; ++k2) {
                wv[k2][0] = *reinterpret_cast<const float4*>(&ws[(kq * 4 + k2) * 128 + cx]);
                wv[k2][1] = *reinterpret_cast<const float4*>(&ws[(kq * 4 + k2) * 128 + cx + 4]);
            }
#pragma unroll
            for (int r = 0; r < 8; ++r) {
                const float* xf = reinterpret_cast<const float*>(&xv[r]);
#pragma unroll
                for (int k2 = 0; k2 < 4; ++k2) {
                    const float xx = xf[k2];
                    const float* w0 = reinterpret_cast<const float*>(&wv[k2][0]);
                    const float* w1 = reinterpret_cast<const float*>(&wv[k2][1]);
#pragma unroll
                    for (int c = 0; c < 4; ++c) {
                        acc[r][c] = fmaf(xx, w0[c], acc[r][c]);
                        acc[r][c + 4] = fmaf(xx, w1[c], acc[r][c + 4]);
                    }
                }
            }
        }
    }
#pragma unroll
    for (int r = 0; r < 8; ++r) {
        int gr = nbase + ry + r;
        if (gr < N_NODES) {
            __half hb[8];
#pragma unroll
            for (int c = 0; c < 8; ++c) hb[c] = __float2half_rn(acc[r][c]);
            *reinterpret_cast<uint4*>(&h16[(size_t)gr * 128 + cx]) =
                *reinterpret_cast<const uint4*>(hb);
        }
    }

    // ---- fused a_src / a_dst epilogue from fp32 accumulators ----
    float asv[8], adv[8];
#pragma unroll
    for (int c = 0; c < 8; ++c) {
        asv[c] = att_src[cx + c];
        adv[c] = att_dst[cx + c];
    }
    __syncthreads();
#pragma unroll
    for (int r = 0; r < 8; ++r) {
        float ps = 0.f, pd = 0.f;
#pragma unroll
        for (int c = 0; c < 8; ++c) {
            ps = fmaf(acc[r][c], asv[c], ps);
            pd = fmaf(acc[r][c], adv[c], pd);
        }
        xs[(ry + r) * 16 + (t & 15)] = ps;
        xs[2048 + (ry + r) * 16 + (t & 15)] = pd;
    }
    __syncthreads();
    for (int idx = t; idx < 1024; idx += 256) {
        int row = idx >> 3, hd = idx & 7;
        int gr = nbase + row;
        if (gr < N_NODES) {
            a_srcp[gr * 8 + hd] = xs[row * 16 + hd * 2] + xs[row * 16 + hd * 2 + 1];
            a_dstp[gr * 8 + hd] = xs[2048 + row * 16 + hd * 2] + xs[2048 + row * 16 + hd * 2 + 1];
        }
    }
}

// ---------------- bucket histogram (bucket = dst >> 7) ----------------
__global__ __launch_bounds__(256) void bucket_hist_kernel(const int* __restrict__ ei,
                                                          int* __restrict__ bucket_count) {
    __shared__ int hist[NB];
    for (int i = threadIdx.x; i < NB; i += 256) hist[i] = 0;
    __syncthreads();
    const int4* dsts = reinterpret_cast<const int4*>(ei + N_EDGES);
    const int base = blockIdx.x * 2048;       // int4 units (8192 edges per block)
    for (int i = threadIdx.x; i < 2048; i += 256) {
        int idx = base + i;
        if (idx < N_EDGES / 4) {
            int4 d = dsts[idx];
            atomicAdd(&hist[d.x >> 7], 1);
            atomicAdd(&hist[d.y >> 7], 1);
            atomicAdd(&hist[d.z >> 7], 1);
            atomicAdd(&hist[d.w >> 7], 1);
        }
    }
    __syncthreads();
    for (int i = threadIdx.x; i < NB; i += 256) {
        int c = hist[i];
        if (c) atomicAdd(&bucket_count[i], c);
    }
}

// ---------------- exclusive scan over bucket counts (1 block) ----------------
__global__ __launch_bounds__(256) void bucket_scan_kernel(const int* __restrict__ bucket_count,
                                                          int* __restrict__ bucket_base,
                                                          int* __restrict__ bucket_cursor) {
    __shared__ int sdata[256];
    const int t = threadIdx.x;
    const int g = t * 4;
    int v[4];
#pragma unroll
    for (int j = 0; j < 4; ++j) v[j] = (g + j < NB) ? bucket_count[g + j] : 0;
    int tot = v[0] + v[1] + v[2] + v[3];
    sdata[t] = tot;
    __syncthreads();
    for (int off = 1; off < 256; off <<= 1) {
        int u = (t >= off) ? sdata[t - off] : 0;
        __syncthreads();
        sdata[t] += u;
        __syncthreads();
    }
    int run = sdata[t] - tot;
#pragma unroll
    for (int j = 0; j < 4; ++j) {
        if (g + j < NB) {
            bucket_base[g + j] = run;
            bucket_cursor[g + j] = run;
        }
        run += v[j];
    }
    if (t == 255) bucket_base[NB] = sdata[255];   // == N_EDGES
}

// ---------------- bin edges into bucket-grouped (src,dst) pairs ----------------
__global__ __launch_bounds__(256) void bin_kernel(const int* __restrict__ ei,
                                                  int* __restrict__ bucket_cursor,
                                                  uint2* __restrict__ binned) {
    __shared__ int hist[NB];
    __shared__ int cbase[NB];
    __shared__ int psrc[4096];
    __shared__ int pdst[4096];
    const int t = threadIdx.x;
    const int e0 = blockIdx.x * 4096;
    for (int i = t; i < NB; i += 256) hist[i] = 0;
    __syncthreads();
    for (int i = t; i < 4096; i += 256) {
        int e = e0 + i;
        int d = -1, s_ = 0;
        if (e < N_EDGES) {
            s_ = ei[e];
            d = ei[N_EDGES + e];
            atomicAdd(&hist[d >> 7], 1);
        }
        psrc[i] = s_;
        pdst[i] = d;
    }
    __syncthreads();
    // reserve one contiguous run per bucket for this block
    for (int i = t; i < NB; i += 256) {
        int c = hist[i];
        cbase[i] = c ? atomicAdd(&bucket_cursor[i], c) : 0;
    }
    __syncthreads();
    for (int i = t; i < NB; i += 256) hist[i] = 0;   // reuse as local cursor
    __syncthreads();
    for (int i = t; i < 4096; i += 256) {
        int d = pdst[i];
        if (d >= 0) {
            int bk = d >> 7;
            int off = atomicAdd(&hist[bk], 1);
            binned[cbase[bk] + off] = make_uint2((unsigned)psrc[i], (unsigned)d);
        }
    }
}

// ---------------- build rowptr + csr_src, one block per bucket ----------------
__global__ __launch_bounds__(256) void csr_build_kernel(const uint2* __restrict__ binned,
                                                        const int* __restrict__ bucket_base,
                                                        int* __restrict__ rowptr,
                                                        int* __restrict__ csr_src) {
    __shared__ int deg[128];
    __shared__ int sc[128];
    __shared__ int cur[128];
    const int b = blockIdx.x;
    const int t = threadIdx.x;
    const int base = bucket_base[b];
    const int cnt = bucket_base[b + 1] - base;
    const int n0 = b << 7;
    if (t < 128) deg[t] = 0;
    __syncthreads();
    for (int i = t; i < cnt; i += 256)
        atomicAdd(&deg[binned[base + i].y & 127], 1);
    __syncthreads();
    if (t < 128) sc[t] = deg[t];
    __syncthreads();
    for (int off = 1; off < 128; off <<= 1) {
        int u = (t < 128 && t >= off) ? sc[t - off] : 0;
        __syncthreads();
        if (t < 128) sc[t] += u;
        __syncthreads();
    }
    if (t < 128) {
        int excl = sc[t] - deg[t];
        cur[t] = excl;
        int n = n0 + t;
        if (n < N_NODES) rowptr[n] = base + excl;
    }
    if (b == NB - 1 && t == 0) rowptr[N_NODES] = N_EDGES;
    __syncthreads();
    for (int i = t; i < cnt; i += 256) {
        uint2 pr = binned[base + i];
        int off = atomicAdd(&cur[pr.y & 127], 1);
        csr_src[base + off] = (int)pr.x;
    }
}

// ---------------- fused per-node aggregate + softmax + LN (unchanged from R3) ----
__global__ __launch_bounds__(256) void node_aggregate_kernel(const int* __restrict__ rowptr,
                                                             const int* __restrict__ csr_src,
                                                             const __half* __restrict__ h16,
                                                             const float* __restrict__ a_srcp,
                                                             const float* __restrict__ a_dstp,
                                                             const float* __restrict__ x,
                                                             const float* __restrict__ bias,
                                                             const float* __restrict__ gamma,
                                                             const float* __restrict__ beta,
                                                             float* __restrict__ out) {
    int node = blockIdx.x * 4 + (threadIdx.x >> 6);
    if (node >= N_NODES) return;
    const int lane = threadIdx.x & 63;
    const int q = lane >> 4;           // quarter 0..3
    const int ql = lane & 15;          // lane within quarter
    const int ch = ql * 8;             // 8 channels per lane
    const int head = ql >> 1;          // 2 lanes per head

    const float adst = a_dstp[node * 8 + head];

    const int beg = rowptr[node];
    const int end = rowptr[node + 1];

    float s = 0.f;
    float accv[8] = {};

    const uint4* __restrict__ hp = reinterpret_cast<const uint4*>(h16);  // row = 16 uint4

    int i = beg + q;
    if (i < end) {
        const int sF = csr_src[i];
        int s1 = (i + 4 < end) ? csr_src[i + 4] : sF;
        uint4 hv = hp[(size_t)sF * 16 + ql];
        float as = a_srcp[sF * 8 + head];
        while (true) {
            const uint4 hc = hv;
            const float ac = as;
            const int sN = s1;
            const int i8 = i + 8;
            s1 = (i8 < end) ? csr_src[i8] : sF;
            hv = hp[(size_t)sN * 16 + ql];
            as = a_srcp[sN * 8 + head];

            float e = ac + adst;
            e = e >= 0.f ? e : NEG_SLOPE * e;
            e = fminf(e, 80.f);
            const float p = __expf(e);
            s += p;
            const __half2* hh = reinterpret_cast<const __half2*>(&hc);
#pragma unroll
            for (int j = 0; j < 4; ++j) {
                const float2 f = __half22float2(hh[j]);
                accv[2 * j] = fmaf(p, f.x, accv[2 * j]);
                accv[2 * j + 1] = fmaf(p, f.y, accv[2 * j + 1]);
            }

            i += 4;
            if (i >= end) break;
        }
    }

    s += __shfl_xor(s, 16);
    s += __shfl_xor(s, 32);
#pragma unroll
    for (int j = 0; j < 8; ++j) {
        accv[j] += __shfl_xor(accv[j], 16);
        accv[j] += __shfl_xor(accv[j], 32);
    }

    const float rs = 1.0f / (s + 1e-16f);
    const float* xrp = x + (size_t)node * 128 + ch;
    float v[8];
#pragma unroll
    for (int j = 0; j < 8; ++j) {
        const float xr = __builtin_nontemporal_load(xrp + j);
        v[j] = accv[j] * rs + bias[ch + j] + xr;
    }

    float sum = 0.f, sq = 0.f;
#pragma unroll
    for (int j = 0; j < 8; ++j) {
        sum += v[j];
        sq = fmaf(v[j], v[j], sq);
    }
#pragma unroll
    for (int off = 32; off > 0; off >>= 1) {
        sum += __shfl_xor(sum, off);
        sq += __shfl_xor(sq, off);
    }
    const float mu = sum * (1.0f / 512.0f);
    const float var = sq * (1.0f / 512.0f) - mu * mu;
    const float inv = rsqrtf(var + LN_EPS);
    if (q == 0) {
        float o[8];
#pragma unroll
        for (int j = 0; j < 8; ++j) {
            float tt = (v[j] - mu) * inv * gamma[ch + j] + beta[ch + j];
            o[j] = tt > 0.f ? tt : 0.f;
        }
        float* op = out + (size_t)node * 128 + ch;
#pragma unroll
        for (int j = 0; j < 8; ++j) __builtin_nontemporal_store(o[j], op + j);
    }
}

extern "C" void kernel_launch(void* const* d_in, const int* in_sizes, int n_in,
                              void* d_out, int out_size, void* d_ws, size_t ws_size,
                              hipStream_t stream) {
    const float* x = (const float*)d_in[0];
    const int* ei = (const int*)d_in[1];
    const float* W = (const float*)d_in[2];
    const float* att_src = (const float*)d_in[3];
    const float* att_dst = (const float*)d_in[4];
    const float* bias = (const float*)d_in[5];
    const float* gamma = (const float*)d_in[6];
    const float* beta = (const float*)d_in[7];
    float* out = (float*)d_out;

    char* base = (char*)d_ws;
    __half* h16   = (__half*)base;                      // 25.6 MB
    float* a_srcp = (float*)(base + 25600000);          // 3.2 MB
    float* a_dstp = (float*)(base + 28800000);          // 3.2 MB
    int* csr_src  = (int*)(base + 32000000);            // 6.4 MB
    int* rowptr   = (int*)(base + 38400000);            // 400,004 B (pad to 38,800,128)
    uint2* binned = (uint2*)(base + 38800128);          // 12.8 MB
    int* bucket_count  = (int*)(base + 51600128);       // 3,128 B
    int* bucket_base   = (int*)(base + 51603264);       // 3,132 B
    int* bucket_cursor = (int*)(base + 51606400);       // 3,128 B

    hipMemsetAsync(bucket_count, 0, NB * sizeof(int), stream);
    gemm_kernel<<<(N_NODES + 127) / 128, 256, 0, stream>>>(x, W, att_src, att_dst,
                                                           h16, a_srcp, a_dstp);
    bucket_hist_kernel<<<(N_EDGES / 4 + 2047) / 2048, 256, 0, stream>>>(ei, bucket_count);
    bucket_scan_kernel<<<1, 256, 0, stream>>>(bucket_count, bucket_base, bucket_cursor);
    bin_kernel<<<(N_EDGES + 4095) / 4096, 256, 0, stream>>>(ei, bucket_cursor, binned);
    csr_build_kernel<<<NB, 256, 0, stream>>>(binned, bucket_base, rowptr, csr_src);
    node_aggregate_kernel<<<(N_NODES + 3) / 4, 256, 0, stream>>>(
        rowptr, csr_src, h16, a_srcp, a_dstp, x, bias, gamma, beta, out);
}

// Round 5
// 184.555 us; speedup vs baseline: 2.2750x; 1.0945x over previous
//
#include <hip/hip_runtime.h>
#include <hip/hip_fp16.h>

#define N_NODES 100000
#define N_EDGES 1600000
#define NEG_SLOPE 0.2f
#define LN_EPS 1e-5f
#define NB 782            // ceil(N_NODES / 128) buckets, bucket = dst >> 7
#define GEMM_BLOCKS 782   // ceil(N_NODES / 128)
#define HIST_BLOCKS 196   // ceil(N_EDGES / 8192)
#define BIN_EDGES 8192
#define CSR_CAP 2816      // LDS stage capacity per bucket (mean 2046, +17 sigma)

// ---------------- fused GEMM + bucket-hist mega-kernel ----------------
// blocks [0, GEMM_BLOCKS): h16 = fp16(x @ W), fused a_src(fp16)/a_dst(fp32) epilogue.
// blocks [GEMM_BLOCKS, GEMM_BLOCKS+HIST_BLOCKS): bucket histogram of dst>>7.
__global__ __launch_bounds__(256) void gemm_hist_kernel(const float* __restrict__ x,
                                                        const float* __restrict__ W,
                                                        const float* __restrict__ att_src,
                                                        const float* __restrict__ att_dst,
                                                        const int* __restrict__ ei,
                                                        __half* __restrict__ h16,
                                                        __half* __restrict__ a_srcp,
                                                        float* __restrict__ a_dstp,
                                                        int* __restrict__ bucket_count) {
    __shared__ float xs[128 * 64];   // [r][k]  32 KB (reused by epilogue / hist)
    __shared__ float ws[64 * 128];   // [k][c]  32 KB
    const int t = threadIdx.x;

    if (blockIdx.x >= GEMM_BLOCKS) {
        // ---------------- bucket histogram branch ----------------
        int* hist = reinterpret_cast<int*>(xs);
        for (int i = t; i < NB; i += 256) hist[i] = 0;
        __syncthreads();
        const int4* dsts = reinterpret_cast<const int4*>(ei + N_EDGES);
        const int base = (blockIdx.x - GEMM_BLOCKS) * (BIN_EDGES / 4);
        for (int i = t; i < BIN_EDGES / 4; i += 256) {
            int idx = base + i;
            if (idx < N_EDGES / 4) {
                int4 d = dsts[idx];
                atomicAdd(&hist[d.x >> 7], 1);
                atomicAdd(&hist[d.y >> 7], 1);
                atomicAdd(&hist[d.z >> 7], 1);
                atomicAdd(&hist[d.w >> 7], 1);
            }
        }
        __syncthreads();
        for (int i = t; i < NB; i += 256) {
            int c = hist[i];
            if (c) atomicAdd(&bucket_count[i], c);
        }
        return;
    }

    // ---------------- GEMM branch ----------------
    const int nbase = blockIdx.x * 128;
    const int cx = (t & 15) * 8;     // 8 consecutive output cols
    const int ry = (t >> 4) * 8;     // 8 consecutive output rows
    float acc[8][8] = {};
    for (int kb = 0; kb < 2; ++kb) {
        __syncthreads();
        for (int i = t; i < 2048; i += 256) {
            int r = i >> 4, kq = i & 15;
            int gr = nbase + r;
            gr = gr < N_NODES ? gr : N_NODES - 1;
            *reinterpret_cast<float4*>(&xs[r * 64 + kq * 4]) =
                *reinterpret_cast<const float4*>(&x[(size_t)gr * 128 + kb * 64 + kq * 4]);
        }
        for (int i = t; i < 2048; i += 256) {
            int k = i >> 5, cq = i & 31;
            *reinterpret_cast<float4*>(&ws[k * 128 + cq * 4]) =
                *reinterpret_cast<const float4*>(&W[(size_t)(kb * 64 + k) * 128 + cq * 4]);
        }
        __syncthreads();
        for (int kq = 0; kq < 16; ++kq) {
            float4 xv[8];
            float4 wv[4][2];
#pragma unroll
            for (int r = 0; r < 8; ++r)
                xv[r] = *reinterpret_cast<const float4*>(&xs[(ry + r) * 64 + kq * 4]);
#pragma unroll
            for (int k2 = 0; k2 < 4; ++k2) {
                wv[k2][0] = *reinterpret_cast<const float4*>(&ws[(kq * 4 + k2) * 128 + cx]);
                wv[k2][1] = *reinterpret_cast<const float4*>(&ws[(kq * 4 + k2) * 128 + cx + 4]);
            }
#pragma unroll
            for (int r = 0; r < 8; ++r) {
                const float* xf = reinterpret_cast<const float*>(&xv[r]);
#pragma unroll
                for (int k2 = 0; k2 < 4; ++k2) {
                    const float xx = xf[k2];
                    const float* w0 = reinterpret_cast<const float*>(&wv[k2][0]);
                    const float* w1 = reinterpret_cast<const float*>(&wv[k2][1]);
#pragma unroll
                    for (int c = 0; c < 4; ++c) {
                        acc[r][c] = fmaf(xx, w0[c], acc[r][c]);
                        acc[r][c + 4] = fmaf(xx, w1[c], acc[r][c + 4]);
                    }
                }
            }
        }
    }
#pragma unroll
    for (int r = 0; r < 8; ++r) {
        int gr = nbase + ry + r;
        if (gr < N_NODES) {
            __half hb[8];
#pragma unroll
            for (int c = 0; c < 8; ++c) hb[c] = __float2half_rn(acc[r][c]);
            *reinterpret_cast<uint4*>(&h16[(size_t)gr * 128 + cx]) =
                *reinterpret_cast<const uint4*>(hb);
        }
    }

    // ---- fused a_src / a_dst epilogue from fp32 accumulators ----
    float asv[8], adv[8];
#pragma unroll
    for (int c = 0; c < 8; ++c) {
        asv[c] = att_src[cx + c];
        adv[c] = att_dst[cx + c];
    }
    __syncthreads();
#pragma unroll
    for (int r = 0; r < 8; ++r) {
        float ps = 0.f, pd = 0.f;
#pragma unroll
        for (int c = 0; c < 8; ++c) {
            ps = fmaf(acc[r][c], asv[c], ps);
            pd = fmaf(acc[r][c], adv[c], pd);
        }
        xs[(ry + r) * 16 + (t & 15)] = ps;
        xs[2048 + (ry + r) * 16 + (t & 15)] = pd;
    }
    __syncthreads();
    for (int idx = t; idx < 1024; idx += 256) {
        int row = idx >> 3, hd = idx & 7;
        int gr = nbase + row;
        if (gr < N_NODES) {
            a_srcp[gr * 8 + hd] =
                __float2half_rn(xs[row * 16 + hd * 2] + xs[row * 16 + hd * 2 + 1]);
            a_dstp[gr * 8 + hd] = xs[2048 + row * 16 + hd * 2] + xs[2048 + row * 16 + hd * 2 + 1];
        }
    }
}

// ---------------- exclusive scan over bucket counts (1 block) ----------------
__global__ __launch_bounds__(256) void bucket_scan_kernel(const int* __restrict__ bucket_count,
                                                          int* __restrict__ bucket_base,
                                                          int* __restrict__ bucket_cursor) {
    __shared__ int sdata[256];
    const int t = threadIdx.x;
    const int g = t * 4;
    int v[4];
#pragma unroll
    for (int j = 0; j < 4; ++j) v[j] = (g + j < NB) ? bucket_count[g + j] : 0;
    int tot = v[0] + v[1] + v[2] + v[3];
    sdata[t] = tot;
    __syncthreads();
    for (int off = 1; off < 256; off <<= 1) {
        int u = (t >= off) ? sdata[t - off] : 0;
        __syncthreads();
        sdata[t] += u;
        __syncthreads();
    }
    int run = sdata[t] - tot;
#pragma unroll
    for (int j = 0; j < 4; ++j) {
        if (g + j < NB) {
            bucket_base[g + j] = run;
            bucket_cursor[g + j] = run;
        }
        run += v[j];
    }
    if (t == 255) bucket_base[NB] = sdata[255];   // == N_EDGES
}

// ---------------- bin edges into bucket-grouped packed entries ----------------
// packed = (src << 7) | (dst & 127); bucket = dst >> 7 implicit in position.
__global__ __launch_bounds__(256) void bin_kernel(const int* __restrict__ ei,
                                                  int* __restrict__ bucket_cursor,
                                                  unsigned* __restrict__ binned) {
    __shared__ int hist[NB];
    __shared__ int cbase[NB];
    const int t = threadIdx.x;
    const int e0 = blockIdx.x * BIN_EDGES;
    for (int i = t; i < NB; i += 256) hist[i] = 0;
    __syncthreads();
    // pass 1: local histogram (vectorized dst reads)
    const int4* dsts = reinterpret_cast<const int4*>(ei + N_EDGES);
    const int b4 = e0 >> 2;
    for (int i = t; i < BIN_EDGES / 4; i += 256) {
        int idx = b4 + i;
        if (idx < N_EDGES / 4) {
            int4 d = dsts[idx];
            atomicAdd(&hist[d.x >> 7], 1);
            atomicAdd(&hist[d.y >> 7], 1);
            atomicAdd(&hist[d.z >> 7], 1);
            atomicAdd(&hist[d.w >> 7], 1);
        }
    }
    __syncthreads();
    // reserve one contiguous run per bucket for this block
    for (int i = t; i < NB; i += 256) {
        int c = hist[i];
        cbase[i] = c ? atomicAdd(&bucket_cursor[i], c) : 0;
    }
    __syncthreads();
    for (int i = t; i < NB; i += 256) hist[i] = 0;   // reuse as local cursor
    __syncthreads();
    // pass 2: scatter packed entries (ei re-read is L2-hot)
    for (int i = t; i < BIN_EDGES; i += 256) {
        int e = e0 + i;
        if (e < N_EDGES) {
            int s_ = ei[e];
            int d = ei[N_EDGES + e];
            int bk = d >> 7;
            int off = atomicAdd(&hist[bk], 1);
            binned[cbase[bk] + off] = (unsigned)((s_ << 7) | (d & 127));
        }
    }
}

// ---------------- build rowptr + csr_src, one block per bucket ----------------
__global__ __launch_bounds__(256) void csr_build_kernel(const unsigned* __restrict__ binned,
                                                        const int* __restrict__ bucket_base,
                                                        int* __restrict__ rowptr,
                                                        int* __restrict__ csr_src) {
    __shared__ int deg[128];
    __shared__ int sc[128];
    __shared__ int cur[128];
    __shared__ unsigned stage[CSR_CAP];
    const int b = blockIdx.x;
    const int t = threadIdx.x;
    const int base = bucket_base[b];
    const int cnt = bucket_base[b + 1] - base;
    const int n0 = b << 7;
    const bool fits = cnt <= CSR_CAP;
    if (t < 128) deg[t] = 0;
    __syncthreads();
    if (fits) {
        for (int i = t; i < cnt; i += 256) {
            unsigned p = binned[base + i];
            stage[i] = p;
            atomicAdd(&deg[p & 127], 1);
        }
    } else {
        for (int i = t; i < cnt; i += 256)
            atomicAdd(&deg[binned[base + i] & 127], 1);
    }
    __syncthreads();
    if (t < 128) sc[t] = deg[t];
    __syncthreads();
    for (int off = 1; off < 128; off <<= 1) {
        int u = (t < 128 && t >= off) ? sc[t - off] : 0;
        __syncthreads();
        if (t < 128) sc[t] += u;
        __syncthreads();
    }
    if (t < 128) {
        int excl = sc[t] - deg[t];
        cur[t] = excl;
        int n = n0 + t;
        if (n < N_NODES) rowptr[n] = base + excl;
    }
    if (b == NB - 1 && t == 0) rowptr[N_NODES] = N_EDGES;
    __syncthreads();
    if (fits) {
        for (int i = t; i < cnt; i += 256) {
            unsigned p = stage[i];
            int off = atomicAdd(&cur[p & 127], 1);
            csr_src[base + off] = (int)(p >> 7);
        }
    } else {
        for (int i = t; i < cnt; i += 256) {
            unsigned p = binned[base + i];
            int off = atomicAdd(&cur[p & 127], 1);
            csr_src[base + off] = (int)(p >> 7);
        }
    }
}

// ---------------- fused per-node aggregate + softmax + LN ----------------
// one 64-lane wave per node, split into four 16-lane quarters; quarter q owns
// edges beg+q, beg+q+4, ...; lane-within-quarter ql owns channels 8*ql..8*ql+7.
__global__ __launch_bounds__(256) void node_aggregate_kernel(const int* __restrict__ rowptr,
                                                             const int* __restrict__ csr_src,
                                                             const __half* __restrict__ h16,
                                                             const __half* __restrict__ a_srcp,
                                                             const float* __restrict__ a_dstp,
                                                             const float* __restrict__ x,
                                                             const float* __restrict__ bias,
                                                             const float* __restrict__ gamma,
                                                             const float* __restrict__ beta,
                                                             float* __restrict__ out) {
    int node = blockIdx.x * 4 + (threadIdx.x >> 6);
    if (node >= N_NODES) return;
    const int lane = threadIdx.x & 63;
    const int q = lane >> 4;           // quarter 0..3
    const int ql = lane & 15;          // lane within quarter
    const int ch = ql * 8;             // 8 channels per lane
    const int head = ql >> 1;          // 2 lanes per head

    const float adst = a_dstp[node * 8 + head];

    const int beg = rowptr[node];
    const int end = rowptr[node + 1];

    float s = 0.f;
    float accv[8] = {};

    const uint4* __restrict__ hp = reinterpret_cast<const uint4*>(h16);  // row = 16 uint4

    int i = beg + q;
    if (i < end) {
        const int sF = csr_src[i];
        int s1 = (i + 4 < end) ? csr_src[i + 4] : sF;
        uint4 hv = hp[(size_t)sF * 16 + ql];
        float as = __half2float(a_srcp[sF * 8 + head]);
        while (true) {
            const uint4 hc = hv;
            const float ac = as;
            const int sN = s1;
            const int i8 = i + 8;
            s1 = (i8 < end) ? csr_src[i8] : sF;
            hv = hp[(size_t)sN * 16 + ql];
            as = __half2float(a_srcp[sN * 8 + head]);

            float e = ac + adst;
            e = e >= 0.f ? e : NEG_SLOPE * e;
            e = fminf(e, 80.f);
            const float p = __expf(e);
            s += p;
            const __half* hh = reinterpret_cast<const __half*>(&hc);
#pragma unroll
            for (int j = 0; j < 8; ++j)
                accv[j] = fmaf(p, __half2float(hh[j]), accv[j]);   // v_fma_mix idiom

            i += 4;
            if (i >= end) break;
        }
    }

    s += __shfl_xor(s, 16);
    s += __shfl_xor(s, 32);
#pragma unroll
    for (int j = 0; j < 8; ++j) {
        accv[j] += __shfl_xor(accv[j], 16);
        accv[j] += __shfl_xor(accv[j], 32);
    }

    const float rs = 1.0f / (s + 1e-16f);
    const float* xrp = x + (size_t)node * 128 + ch;
    float v[8];
#pragma unroll
    for (int j = 0; j < 8; ++j) {
        const float xr = __builtin_nontemporal_load(xrp + j);
        v[j] = accv[j] * rs + bias[ch + j] + xr;
    }

    float sum = 0.f, sq = 0.f;
#pragma unroll
    for (int j = 0; j < 8; ++j) {
        sum += v[j];
        sq = fmaf(v[j], v[j], sq);
    }
#pragma unroll
    for (int off = 32; off > 0; off >>= 1) {
        sum += __shfl_xor(sum, off);
        sq += __shfl_xor(sq, off);
    }
    const float mu = sum * (1.0f / 512.0f);
    const float var = sq * (1.0f / 512.0f) - mu * mu;
    const float inv = rsqrtf(var + LN_EPS);
    if (q == 0) {
        float o[8];
#pragma unroll
        for (int j = 0; j < 8; ++j) {
            float tt = (v[j] - mu) * inv * gamma[ch + j] + beta[ch + j];
            o[j] = tt > 0.f ? tt : 0.f;
        }
        float* op = out + (size_t)node * 128 + ch;
#pragma unroll
        for (int j = 0; j < 8; ++j) __builtin_nontemporal_store(o[j], op + j);
    }
}

extern "C" void kernel_launch(void* const* d_in, const int* in_sizes, int n_in,
                              void* d_out, int out_size, void* d_ws, size_t ws_size,
                              hipStream_t stream) {
    const float* x = (const float*)d_in[0];
    const int* ei = (const int*)d_in[1];
    const float* W = (const float*)d_in[2];
    const float* att_src = (const float*)d_in[3];
    const float* att_dst = (const float*)d_in[4];
    const float* bias = (const float*)d_in[5];
    const float* gamma = (const float*)d_in[6];
    const float* beta = (const float*)d_in[7];
    float* out = (float*)d_out;

    char* base = (char*)d_ws;
    __half* h16    = (__half*)base;                     // 25.6 MB
    __half* a_srcp = (__half*)(base + 25600000);        // 1.6 MB
    float* a_dstp  = (float*)(base + 27200000);         // 3.2 MB
    int* csr_src   = (int*)(base + 30400000);           // 6.4 MB
    int* rowptr    = (int*)(base + 36800000);           // 400,004 B (pad)
    unsigned* binned = (unsigned*)(base + 37200128);    // 6.4 MB
    int* bucket_count  = (int*)(base + 43600128);       // 3,128 B
    int* bucket_base   = (int*)(base + 43603264);       // 3,132 B
    int* bucket_cursor = (int*)(base + 43606400);       // 3,128 B

    hipMemsetAsync(bucket_count, 0, NB * sizeof(int), stream);
    gemm_hist_kernel<<<GEMM_BLOCKS + HIST_BLOCKS, 256, 0, stream>>>(
        x, W, att_src, att_dst, ei, h16, a_srcp, a_dstp, bucket_count);
    bucket_scan_kernel<<<1, 256, 0, stream>>>(bucket_count, bucket_base, bucket_cursor);
    bin_kernel<<<(N_EDGES + BIN_EDGES - 1) / BIN_EDGES, 256, 0, stream>>>(ei, bucket_cursor, binned);
    csr_build_kernel<<<NB, 256, 0, stream>>>(binned, bucket_base, rowptr, csr_src);
    node_aggregate_kernel<<<(N_NODES + 3) / 4, 256, 0, stream>>>(
        rowptr, csr_src, h16, a_srcp, a_dstp, x, bias, gamma, beta, out);
}

// Round 7
// 184.211 us; speedup vs baseline: 2.2793x; 1.0019x over previous
//
#include <hip/hip_runtime.h>
#include <hip/hip_fp16.h>

#define N_NODES 100000
#define N_EDGES 1600000
#define NEG_SLOPE 0.2f
#define LN_EPS 1e-5f
#define NB 782            // ceil(N_NODES / 128) buckets, bucket = dst >> 7
#define GEMM_BLOCKS 782   // ceil(N_NODES / 128)
#define HIST_BLOCKS 196   // ceil(N_EDGES / 8192)
#define BIN_EDGES 8192
#define CSR_CAP 2816      // LDS stage capacity per bucket (mean 2046, +17 sigma)

// ---------------- fused GEMM + bucket-hist mega-kernel ----------------
// blocks [0, GEMM_BLOCKS): h16 = fp16(x @ W), fused a_src(fp16)/a_dst(fp32) epilogue.
// blocks [GEMM_BLOCKS, GEMM_BLOCKS+HIST_BLOCKS): bucket histogram of dst>>7.
__global__ __launch_bounds__(256) void gemm_hist_kernel(const float* __restrict__ x,
                                                        const float* __restrict__ W,
                                                        const float* __restrict__ att_src,
                                                        const float* __restrict__ att_dst,
                                                        const int* __restrict__ ei,
                                                        __half* __restrict__ h16,
                                                        __half* __restrict__ a_srcp,
                                                        float* __restrict__ a_dstp,
                                                        int* __restrict__ bucket_count) {
    __shared__ float xs[128 * 64];   // [r][k]  32 KB (reused by epilogue / hist)
    __shared__ float ws[64 * 128];   // [k][c]  32 KB
    const int t = threadIdx.x;

    if (blockIdx.x >= GEMM_BLOCKS) {
        // ---------------- bucket histogram branch ----------------
        int* hist = reinterpret_cast<int*>(xs);
        for (int i = t; i < NB; i += 256) hist[i] = 0;
        __syncthreads();
        const int4* dsts = reinterpret_cast<const int4*>(ei + N_EDGES);
        const int base = (blockIdx.x - GEMM_BLOCKS) * (BIN_EDGES / 4);
        for (int i = t; i < BIN_EDGES / 4; i += 256) {
            int idx = base + i;
            if (idx < N_EDGES / 4) {
                int4 d = dsts[idx];
                atomicAdd(&hist[d.x >> 7], 1);
                atomicAdd(&hist[d.y >> 7], 1);
                atomicAdd(&hist[d.z >> 7], 1);
                atomicAdd(&hist[d.w >> 7], 1);
            }
        }
        __syncthreads();
        for (int i = t; i < NB; i += 256) {
            int c = hist[i];
            if (c) atomicAdd(&bucket_count[i], c);
        }
        return;
    }

    // ---------------- GEMM branch ----------------
    const int nbase = blockIdx.x * 128;
    const int cx = (t & 15) * 8;     // 8 consecutive output cols
    const int ry = (t >> 4) * 8;     // 8 consecutive output rows
    float acc[8][8] = {};
    for (int kb = 0; kb < 2; ++kb) {
        __syncthreads();
        for (int i = t; i < 2048; i += 256) {
            int r = i >> 4, kq = i & 15;
            int gr = nbase + r;
            gr = gr < N_NODES ? gr : N_NODES - 1;
            *reinterpret_cast<float4*>(&xs[r * 64 + kq * 4]) =
                *reinterpret_cast<const float4*>(&x[(size_t)gr * 128 + kb * 64 + kq * 4]);
        }
        for (int i = t; i < 2048; i += 256) {
            int k = i >> 5, cq = i & 31;
            *reinterpret_cast<float4*>(&ws[k * 128 + cq * 4]) =
                *reinterpret_cast<const float4*>(&W[(size_t)(kb * 64 + k) * 128 + cq * 4]);
        }
        __syncthreads();
        for (int kq = 0; kq < 16; ++kq) {
            float4 xv[8];
            float4 wv[4][2];
#pragma unroll
            for (int r = 0; r < 8; ++r)
                xv[r] = *reinterpret_cast<const float4*>(&xs[(ry + r) * 64 + kq * 4]);
#pragma unroll
            for (int k2 = 0; k2 < 4; ++k2) {
                wv[k2][0] = *reinterpret_cast<const float4*>(&ws[(kq * 4 + k2) * 128 + cx]);
                wv[k2][1] = *reinterpret_cast<const float4*>(&ws[(kq * 4 + k2) * 128 + cx + 4]);
            }
#pragma unroll
            for (int r = 0; r < 8; ++r) {
                const float* xf = reinterpret_cast<const float*>(&xv[r]);
#pragma unroll
                for (int k2 = 0; k2 < 4; ++k2) {
                    const float xx = xf[k2];
                    const float* w0 = reinterpret_cast<const float*>(&wv[k2][0]);
                    const float* w1 = reinterpret_cast<const float*>(&wv[k2][1]);
#pragma unroll
                    for (int c = 0; c < 4; ++c) {
                        acc[r][c] = fmaf(xx, w0[c], acc[r][c]);
                        acc[r][c + 4] = fmaf(xx, w1[c], acc[r][c + 4]);
                    }
                }
            }
        }
    }
#pragma unroll
    for (int r = 0; r < 8; ++r) {
        int gr = nbase + ry + r;
        if (gr < N_NODES) {
            __half hb[8];
#pragma unroll
            for (int c = 0; c < 8; ++c) hb[c] = __float2half_rn(acc[r][c]);
            *reinterpret_cast<uint4*>(&h16[(size_t)gr * 128 + cx]) =
                *reinterpret_cast<const uint4*>(hb);
        }
    }

    // ---- fused a_src / a_dst epilogue from fp32 accumulators ----
    float asv[8], adv[8];
#pragma unroll
    for (int c = 0; c < 8; ++c) {
        asv[c] = att_src[cx + c];
        adv[c] = att_dst[cx + c];
    }
    __syncthreads();
#pragma unroll
    for (int r = 0; r < 8; ++r) {
        float ps = 0.f, pd = 0.f;
#pragma unroll
        for (int c = 0; c < 8; ++c) {
            ps = fmaf(acc[r][c], asv[c], ps);
            pd = fmaf(acc[r][c], adv[c], pd);
        }
        xs[(ry + r) * 16 + (t & 15)] = ps;
        xs[2048 + (ry + r) * 16 + (t & 15)] = pd;
    }
    __syncthreads();
    for (int idx = t; idx < 1024; idx += 256) {
        int row = idx >> 3, hd = idx & 7;
        int gr = nbase + row;
        if (gr < N_NODES) {
            a_srcp[gr * 8 + hd] =
                __float2half_rn(xs[row * 16 + hd * 2] + xs[row * 16 + hd * 2 + 1]);
            a_dstp[gr * 8 + hd] = xs[2048 + row * 16 + hd * 2] + xs[2048 + row * 16 + hd * 2 + 1];
        }
    }
}

// ---------------- exclusive scan over bucket counts (1 block) ----------------
__global__ __launch_bounds__(256) void bucket_scan_kernel(const int* __restrict__ bucket_count,
                                                          int* __restrict__ bucket_base,
                                                          int* __restrict__ bucket_cursor) {
    __shared__ int sdata[256];
    const int t = threadIdx.x;
    const int g = t * 4;
    int v[4];
#pragma unroll
    for (int j = 0; j < 4; ++j) v[j] = (g + j < NB) ? bucket_count[g + j] : 0;
    int tot = v[0] + v[1] + v[2] + v[3];
    sdata[t] = tot;
    __syncthreads();
    for (int off = 1; off < 256; off <<= 1) {
        int u = (t >= off) ? sdata[t - off] : 0;
        __syncthreads();
        sdata[t] += u;
        __syncthreads();
    }
    int run = sdata[t] - tot;
#pragma unroll
    for (int j = 0; j < 4; ++j) {
        if (g + j < NB) {
            bucket_base[g + j] = run;
            bucket_cursor[g + j] = run;
        }
        run += v[j];
    }
    if (t == 255) bucket_base[NB] = sdata[255];   // == N_EDGES
}

// ---------------- bin edges into bucket-grouped packed entries ----------------
// packed = (src << 7) | (dst & 127); bucket = dst >> 7 implicit in position.
__global__ __launch_bounds__(256) void bin_kernel(const int* __restrict__ ei,
                                                  int* __restrict__ bucket_cursor,
                                                  unsigned* __restrict__ binned) {
    __shared__ int hist[NB];
    __shared__ int cbase[NB];
    const int t = threadIdx.x;
    const int e0 = blockIdx.x * BIN_EDGES;
    for (int i = t; i < NB; i += 256) hist[i] = 0;
    __syncthreads();
    // pass 1: local histogram (vectorized dst reads)
    const int4* dsts = reinterpret_cast<const int4*>(ei + N_EDGES);
    const int b4 = e0 >> 2;
    for (int i = t; i < BIN_EDGES / 4; i += 256) {
        int idx = b4 + i;
        if (idx < N_EDGES / 4) {
            int4 d = dsts[idx];
            atomicAdd(&hist[d.x >> 7], 1);
            atomicAdd(&hist[d.y >> 7], 1);
            atomicAdd(&hist[d.z >> 7], 1);
            atomicAdd(&hist[d.w >> 7], 1);
        }
    }
    __syncthreads();
    // reserve one contiguous run per bucket for this block
    for (int i = t; i < NB; i += 256) {
        int c = hist[i];
        cbase[i] = c ? atomicAdd(&bucket_cursor[i], c) : 0;
    }
    __syncthreads();
    for (int i = t; i < NB; i += 256) hist[i] = 0;   // reuse as local cursor
    __syncthreads();
    // pass 2: scatter packed entries (ei re-read is L2-hot)
    for (int i = t; i < BIN_EDGES; i += 256) {
        int e = e0 + i;
        if (e < N_EDGES) {
            int s_ = ei[e];
            int d = ei[N_EDGES + e];
            int bk = d >> 7;
            int off = atomicAdd(&hist[bk], 1);
            binned[cbase[bk] + off] = (unsigned)((s_ << 7) | (d & 127));
        }
    }
}

// ---------------- build rowptr + csr_src, one block per bucket ----------------
__global__ __launch_bounds__(256) void csr_build_kernel(const unsigned* __restrict__ binned,
                                                        const int* __restrict__ bucket_base,
                                                        int* __restrict__ rowptr,
                                                        int* __restrict__ csr_src) {
    __shared__ int deg[128];
    __shared__ int sc[128];
    __shared__ int cur[128];
    __shared__ unsigned stage[CSR_CAP];
    const int b = blockIdx.x;
    const int t = threadIdx.x;
    const int base = bucket_base[b];
    const int cnt = bucket_base[b + 1] - base;
    const int n0 = b << 7;
    const bool fits = cnt <= CSR_CAP;
    if (t < 128) deg[t] = 0;
    __syncthreads();
    if (fits) {
        for (int i = t; i < cnt; i += 256) {
            unsigned p = binned[base + i];
            stage[i] = p;
            atomicAdd(&deg[p & 127], 1);
        }
    } else {
        for (int i = t; i < cnt; i += 256)
            atomicAdd(&deg[binned[base + i] & 127], 1);
    }
    __syncthreads();
    if (t < 128) sc[t] = deg[t];
    __syncthreads();
    for (int off = 1; off < 128; off <<= 1) {
        int u = (t < 128 && t >= off) ? sc[t - off] : 0;
        __syncthreads();
        if (t < 128) sc[t] += u;
        __syncthreads();
    }
    if (t < 128) {
        int excl = sc[t] - deg[t];
        cur[t] = excl;
        int n = n0 + t;
        if (n < N_NODES) rowptr[n] = base + excl;
    }
    if (b == NB - 1 && t == 0) rowptr[N_NODES] = N_EDGES;
    __syncthreads();
    if (fits) {
        for (int i = t; i < cnt; i += 256) {
            unsigned p = stage[i];
            int off = atomicAdd(&cur[p & 127], 1);
            csr_src[base + off] = (int)(p >> 7);
        }
    } else {
        for (int i = t; i < cnt; i += 256) {
            unsigned p = binned[base + i];
            int off = atomicAdd(&cur[p & 127], 1);
            csr_src[base + off] = (int)(p >> 7);
        }
    }
}

// ---------------- fused per-node aggregate + softmax + LN ----------------
// one 64-lane wave per node, four 16-lane quarters; quarter q owns edges
// beg+q, beg+q+4, ... with a DEPTH-4 software pipeline (slots A-D, hand-rotated).
// Out-of-range prefetch indices are CLAMPED to end-1 -> redundant gathers hit
// the node's own last row (hot lines), adding zero HBM traffic (R2 lesson).
// lane-within-quarter ql owns channels 8*ql..8*ql+7 (one uint4 of fp16).
// h16 row stride = 128 * 2 B = 256 B  (R6 bug: was 512)
__global__ __launch_bounds__(256) void node_aggregate_kernel(const int* __restrict__ rowptr,
                                                             const int* __restrict__ csr_src,
                                                             const __half* __restrict__ h16,
                                                             const __half* __restrict__ a_srcp,
                                                             const float* __restrict__ a_dstp,
                                                             const float* __restrict__ x,
                                                             const float* __restrict__ bias,
                                                             const float* __restrict__ gamma,
                                                             const float* __restrict__ beta,
                                                             float* __restrict__ out) {
    int node = blockIdx.x * 4 + (threadIdx.x >> 6);
    if (node >= N_NODES) return;
    const int lane = threadIdx.x & 63;
    const int q = lane >> 4;           // quarter 0..3
    const int ql = lane & 15;          // lane within quarter
    const int ch = ql * 8;             // 8 channels per lane
    const int head = ql >> 1;          // 2 lanes per head

    const float adst = a_dstp[node * 8 + head];

    const int beg = rowptr[node];
    const int end = rowptr[node + 1];

    float s = 0.f;
    float accv[8] = {};

    const char* __restrict__ hbase = reinterpret_cast<const char*>(h16);
    const unsigned chb = (unsigned)(ql * 16);   // byte offset of this lane's chunk

#define LOADH(dst_, sidx_) \
    dst_ = *reinterpret_cast<const uint4*>(hbase + ((unsigned)(sidx_) * 256u + chb))
#define LOADA(dst_, sidx_) dst_ = __half2float(a_srcp[(sidx_) * 8 + head])

#define CONSUME(hv_, av_)                                                  \
    {                                                                      \
        float e = (av_) + adst;                                            \
        e = fmaxf(e, NEG_SLOPE * e);                                       \
        e = fminf(e, 80.f);                                                \
        const float p = __expf(e);                                         \
        s += p;                                                            \
        const __half* hh = reinterpret_cast<const __half*>(&(hv_));        \
        _Pragma("unroll")                                                  \
        for (int j = 0; j < 8; ++j)                                        \
            accv[j] = fmaf(p, __half2float(hh[j]), accv[j]);               \
    }

#define REFILL(hv_, av_, iv_)                                              \
    {                                                                      \
        const int ic = inext < end ? inext : endm1;                        \
        const int sn = csr_src[ic];                                        \
        LOADH(hv_, sn);                                                    \
        LOADA(av_, sn);                                                    \
        iv_ = inext;                                                       \
        inext += 4;                                                        \
    }

    const int i0 = beg + q;
    if (i0 < end) {
        const int endm1 = end - 1;
        int iA = i0, iB = i0 + 4, iC = i0 + 8, iD = i0 + 12;
        const int cB = iB < end ? iB : endm1;
        const int cC = iC < end ? iC : endm1;
        const int cD = iD < end ? iD : endm1;
        const int sA = csr_src[iA];
        const int sB = csr_src[cB];
        const int sC = csr_src[cC];
        const int sD = csr_src[cD];
        uint4 hA, hB, hC, hD;
        float aA, aB, aC, aD;
        LOADH(hA, sA); LOADA(aA, sA);
        LOADH(hB, sB); LOADA(aB, sB);
        LOADH(hC, sC); LOADA(aC, sC);
        LOADH(hD, sD); LOADA(aD, sD);
        int inext = i0 + 16;
        for (;;) {
            CONSUME(hA, aA);
            REFILL(hA, aA, iA);
            if (iB >= end) break;
            CONSUME(hB, aB);
            REFILL(hB, aB, iB);
            if (iC >= end) break;
            CONSUME(hC, aC);
            REFILL(hC, aC, iC);
            if (iD >= end) break;
            CONSUME(hD, aD);
            REFILL(hD, aD, iD);
            if (iA >= end) break;
        }
    }
#undef LOADH
#undef LOADA
#undef CONSUME
#undef REFILL

    // combine the four quarters (each channel present in all quarters)
    s += __shfl_xor(s, 16);
    s += __shfl_xor(s, 32);
#pragma unroll
    for (int j = 0; j < 8; ++j) {
        accv[j] += __shfl_xor(accv[j], 16);
        accv[j] += __shfl_xor(accv[j], 32);
    }

    // normalize + bias + residual (x is touch-once: non-temporal)
    const float rs = 1.0f / (s + 1e-16f);
    const float* xrp = x + (size_t)node * 128 + ch;
    float v[8];
#pragma unroll
    for (int j = 0; j < 8; ++j) {
        const float xr = __builtin_nontemporal_load(xrp + j);
        v[j] = accv[j] * rs + bias[ch + j] + xr;
    }

    // LayerNorm over 128 channels (full-wave reduce; every channel counted 4x)
    float sum = 0.f, sq = 0.f;
#pragma unroll
    for (int j = 0; j < 8; ++j) {
        sum += v[j];
        sq = fmaf(v[j], v[j], sq);
    }
#pragma unroll
    for (int off = 32; off > 0; off >>= 1) {
        sum += __shfl_xor(sum, off);
        sq += __shfl_xor(sq, off);
    }
    const float mu = sum * (1.0f / 512.0f);
    const float var = sq * (1.0f / 512.0f) - mu * mu;
    const float inv = rsqrtf(var + LN_EPS);
    if (q == 0) {
        float o[8];
#pragma unroll
        for (int j = 0; j < 8; ++j) {
            float tt = (v[j] - mu) * inv * gamma[ch + j] + beta[ch + j];
            o[j] = tt > 0.f ? tt : 0.f;
        }
        float* op = out + (size_t)node * 128 + ch;
#pragma unroll
        for (int j = 0; j < 8; ++j) __builtin_nontemporal_store(o[j], op + j);
    }
}

extern "C" void kernel_launch(void* const* d_in, const int* in_sizes, int n_in,
                              void* d_out, int out_size, void* d_ws, size_t ws_size,
                              hipStream_t stream) {
    const float* x = (const float*)d_in[0];
    const int* ei = (const int*)d_in[1];
    const float* W = (const float*)d_in[2];
    const float* att_src = (const float*)d_in[3];
    const float* att_dst = (const float*)d_in[4];
    const float* bias = (const float*)d_in[5];
    const float* gamma = (const float*)d_in[6];
    const float* beta = (const float*)d_in[7];
    float* out = (float*)d_out;

    char* base = (char*)d_ws;
    __half* h16    = (__half*)base;                     // 25.6 MB
    __half* a_srcp = (__half*)(base + 25600000);        // 1.6 MB
    float* a_dstp  = (float*)(base + 27200000);         // 3.2 MB
    int* csr_src   = (int*)(base + 30400000);           // 6.4 MB
    int* rowptr    = (int*)(base + 36800000);           // 400,004 B (pad)
    unsigned* binned = (unsigned*)(base + 37200128);    // 6.4 MB
    int* bucket_count  = (int*)(base + 43600128);       // 3,128 B
    int* bucket_base   = (int*)(base + 43603264);       // 3,132 B
    int* bucket_cursor = (int*)(base + 43606400);       // 3,128 B

    hipMemsetAsync(bucket_count, 0, NB * sizeof(int), stream);
    gemm_hist_kernel<<<GEMM_BLOCKS + HIST_BLOCKS, 256, 0, stream>>>(
        x, W, att_src, att_dst, ei, h16, a_srcp, a_dstp, bucket_count);
    bucket_scan_kernel<<<1, 256, 0, stream>>>(bucket_count, bucket_base, bucket_cursor);
    bin_kernel<<<(N_EDGES + BIN_EDGES - 1) / BIN_EDGES, 256, 0, stream>>>(ei, bucket_cursor, binned);
    csr_build_kernel<<<NB, 256, 0, stream>>>(binned, bucket_base, rowptr, csr_src);
    node_aggregate_kernel<<<(N_NODES + 3) / 4, 256, 0, stream>>>(
        rowptr, csr_src, h16, a_srcp, a_dstp, x, bias, gamma, beta, out);
}

// Round 8
// 163.479 us; speedup vs baseline: 2.5683x; 1.1268x over previous
//
#include <hip/hip_runtime.h>
#include <hip/hip_fp16.h>

#define N_NODES 100000
#define N_EDGES 1600000
#define NEG_SLOPE 0.2f
#define LN_EPS 1e-5f
#define NB 782            // ceil(N_NODES / 128) buckets, bucket = dst >> 7
#define GEMM_BLOCKS 782   // ceil(N_NODES / 128)
#define BIN_BLOCKS 196    // ceil(N_EDGES / 8192)
#define BIN_EDGES 8192
#define BUCKET_CAP 4096   // padded per-bucket capacity (mean 2048, sigma 45 -> safe)
#define CSR_CAP 2816      // LDS stage capacity per bucket (global fallback above)

// ---------------- fused GEMM + direct-bin mega-kernel ----------------
// blocks [0, GEMM_BLOCKS): h16 = fp16(x @ W), fused a_src(fp16)/a_dst(fp32) epilogue.
// blocks [GEMM_BLOCKS, +BIN_BLOCKS): two-pass LDS bin of edges into PADDED
// per-bucket regions binned[bucket*BUCKET_CAP + ...] — no hist/scan prerequisite,
// only zeroed bucket_cursor.
__global__ __launch_bounds__(256) void gemm_bin_kernel(const float* __restrict__ x,
                                                       const float* __restrict__ W,
                                                       const float* __restrict__ att_src,
                                                       const float* __restrict__ att_dst,
                                                       const int* __restrict__ ei,
                                                       __half* __restrict__ h16,
                                                       __half* __restrict__ a_srcp,
                                                       float* __restrict__ a_dstp,
                                                       int* __restrict__ bucket_cursor,
                                                       unsigned* __restrict__ binned) {
    __shared__ float xs[128 * 64];   // [r][k]  32 KB (reused by epilogue / bin hist)
    __shared__ float ws[64 * 128];   // [k][c]  32 KB (reused by bin cbase)
    const int t = threadIdx.x;

    if (blockIdx.x >= GEMM_BLOCKS) {
        // ---------------- direct-bin branch ----------------
        int* hist = reinterpret_cast<int*>(xs);
        int* cbase = reinterpret_cast<int*>(ws);
        for (int i = t; i < NB; i += 256) hist[i] = 0;
        __syncthreads();
        const int e0 = (blockIdx.x - GEMM_BLOCKS) * BIN_EDGES;
        // pass 1: local histogram (vectorized dst reads)
        const int4* dsts = reinterpret_cast<const int4*>(ei + N_EDGES);
        const int b4 = e0 >> 2;
        for (int i = t; i < BIN_EDGES / 4; i += 256) {
            int idx = b4 + i;
            if (idx < N_EDGES / 4) {
                int4 d = dsts[idx];
                atomicAdd(&hist[d.x >> 7], 1);
                atomicAdd(&hist[d.y >> 7], 1);
                atomicAdd(&hist[d.z >> 7], 1);
                atomicAdd(&hist[d.w >> 7], 1);
            }
        }
        __syncthreads();
        // reserve one contiguous run per bucket for this block
        for (int i = t; i < NB; i += 256) {
            int c = hist[i];
            cbase[i] = c ? atomicAdd(&bucket_cursor[i], c) : 0;
        }
        __syncthreads();
        for (int i = t; i < NB; i += 256) hist[i] = 0;   // reuse as local cursor
        __syncthreads();
        // pass 2: scatter packed entries (ei re-read is L2-hot)
        for (int i = t; i < BIN_EDGES; i += 256) {
            int e = e0 + i;
            if (e < N_EDGES) {
                int s_ = ei[e];
                int d = ei[N_EDGES + e];
                int bk = d >> 7;
                int off = atomicAdd(&hist[bk], 1);
                binned[bk * BUCKET_CAP + cbase[bk] + off] = (unsigned)((s_ << 7) | (d & 127));
            }
        }
        return;
    }

    // ---------------- GEMM branch ----------------
    const int nbase = blockIdx.x * 128;
    const int cx = (t & 15) * 8;     // 8 consecutive output cols
    const int ry = (t >> 4) * 8;     // 8 consecutive output rows
    float acc[8][8] = {};
    for (int kb = 0; kb < 2; ++kb) {
        __syncthreads();
        for (int i = t; i < 2048; i += 256) {
            int r = i >> 4, kq = i & 15;
            int gr = nbase + r;
            gr = gr < N_NODES ? gr : N_NODES - 1;
            *reinterpret_cast<float4*>(&xs[r * 64 + kq * 4]) =
                *reinterpret_cast<const float4*>(&x[(size_t)gr * 128 + kb * 64 + kq * 4]);
        }
        for (int i = t; i < 2048; i += 256) {
            int k = i >> 5, cq = i & 31;
            *reinterpret_cast<float4*>(&ws[k * 128 + cq * 4]) =
                *reinterpret_cast<const float4*>(&W[(size_t)(kb * 64 + k) * 128 + cq * 4]);
        }
        __syncthreads();
        for (int kq = 0; kq < 16; ++kq) {
            float4 xv[8];
            float4 wv[4][2];
#pragma unroll
            for (int r = 0; r < 8; ++r)
                xv[r] = *reinterpret_cast<const float4*>(&xs[(ry + r) * 64 + kq * 4]);
#pragma unroll
            for (int k2 = 0; k2 < 4; ++k2) {
                wv[k2][0] = *reinterpret_cast<const float4*>(&ws[(kq * 4 + k2) * 128 + cx]);
                wv[k2][1] = *reinterpret_cast<const float4*>(&ws[(kq * 4 + k2) * 128 + cx + 4]);
            }
#pragma unroll
            for (int r = 0; r < 8; ++r) {
                const float* xf = reinterpret_cast<const float*>(&xv[r]);
#pragma unroll
                for (int k2 = 0; k2 < 4; ++k2) {
                    const float xx = xf[k2];
                    const float* w0 = reinterpret_cast<const float*>(&wv[k2][0]);
                    const float* w1 = reinterpret_cast<const float*>(&wv[k2][1]);
#pragma unroll
                    for (int c = 0; c < 4; ++c) {
                        acc[r][c] = fmaf(xx, w0[c], acc[r][c]);
                        acc[r][c + 4] = fmaf(xx, w1[c], acc[r][c + 4]);
                    }
                }
            }
        }
    }
#pragma unroll
    for (int r = 0; r < 8; ++r) {
        int gr = nbase + ry + r;
        if (gr < N_NODES) {
            __half hb[8];
#pragma unroll
            for (int c = 0; c < 8; ++c) hb[c] = __float2half_rn(acc[r][c]);
            *reinterpret_cast<uint4*>(&h16[(size_t)gr * 128 + cx]) =
                *reinterpret_cast<const uint4*>(hb);
        }
    }

    // ---- fused a_src / a_dst epilogue from fp32 accumulators ----
    float asv[8], adv[8];
#pragma unroll
    for (int c = 0; c < 8; ++c) {
        asv[c] = att_src[cx + c];
        adv[c] = att_dst[cx + c];
    }
    __syncthreads();
#pragma unroll
    for (int r = 0; r < 8; ++r) {
        float ps = 0.f, pd = 0.f;
#pragma unroll
        for (int c = 0; c < 8; ++c) {
            ps = fmaf(acc[r][c], asv[c], ps);
            pd = fmaf(acc[r][c], adv[c], pd);
        }
        xs[(ry + r) * 16 + (t & 15)] = ps;
        xs[2048 + (ry + r) * 16 + (t & 15)] = pd;
    }
    __syncthreads();
    for (int idx = t; idx < 1024; idx += 256) {
        int row = idx >> 3, hd = idx & 7;
        int gr = nbase + row;
        if (gr < N_NODES) {
            a_srcp[gr * 8 + hd] =
                __float2half_rn(xs[row * 16 + hd * 2] + xs[row * 16 + hd * 2 + 1]);
            a_dstp[gr * 8 + hd] = xs[2048 + row * 16 + hd * 2] + xs[2048 + row * 16 + hd * 2 + 1];
        }
    }
}

// ---------------- build row_beg/row_end + csr_src (padded), one block/bucket ----
__global__ __launch_bounds__(256) void csr_build_kernel(const unsigned* __restrict__ binned,
                                                        const int* __restrict__ bucket_cursor,
                                                        int* __restrict__ row_beg,
                                                        int* __restrict__ row_end,
                                                        int* __restrict__ csr_src) {
    __shared__ int deg[128];
    __shared__ int sc[128];
    __shared__ int cur[128];
    __shared__ unsigned stage[CSR_CAP];
    const int b = blockIdx.x;
    const int t = threadIdx.x;
    const int pbase = b * BUCKET_CAP;
    const int cnt = bucket_cursor[b];
    const int n0 = b << 7;
    const bool fits = cnt <= CSR_CAP;
    if (t < 128) deg[t] = 0;
    __syncthreads();
    if (fits) {
        for (int i = t; i < cnt; i += 256) {
            unsigned p = binned[pbase + i];
            stage[i] = p;
            atomicAdd(&deg[p & 127], 1);
        }
    } else {
        for (int i = t; i < cnt; i += 256)
            atomicAdd(&deg[binned[pbase + i] & 127], 1);
    }
    __syncthreads();
    if (t < 128) sc[t] = deg[t];
    __syncthreads();
    for (int off = 1; off < 128; off <<= 1) {
        int u = (t < 128 && t >= off) ? sc[t - off] : 0;
        __syncthreads();
        if (t < 128) sc[t] += u;
        __syncthreads();
    }
    if (t < 128) {
        int excl = sc[t] - deg[t];
        cur[t] = excl;
        int n = n0 + t;
        if (n < N_NODES) {
            row_beg[n] = pbase + excl;
            row_end[n] = pbase + excl + deg[t];
        }
    }
    __syncthreads();
    if (fits) {
        for (int i = t; i < cnt; i += 256) {
            unsigned p = stage[i];
            int off = atomicAdd(&cur[p & 127], 1);
            csr_src[pbase + off] = (int)(p >> 7);
        }
    } else {
        for (int i = t; i < cnt; i += 256) {
            unsigned p = binned[pbase + i];
            int off = atomicAdd(&cur[p & 127], 1);
            csr_src[pbase + off] = (int)(p >> 7);
        }
    }
}

// ---------------- fused per-node aggregate + softmax + LN ----------------
// one 64-lane wave per node, four 16-lane quarters; quarter q owns edges
// beg+q, beg+q+4, ... with a DEPTH-4 software pipeline (slots A-D, hand-rotated).
// Out-of-range prefetch indices CLAMPED to end-1 (zero extra HBM traffic).
// lane-within-quarter ql owns channels 8*ql..8*ql+7 (one uint4 of fp16).
// h16 row stride = 128 * 2 B = 256 B.
__global__ __launch_bounds__(256) void node_aggregate_kernel(const int* __restrict__ row_beg,
                                                             const int* __restrict__ row_end,
                                                             const int* __restrict__ csr_src,
                                                             const __half* __restrict__ h16,
                                                             const __half* __restrict__ a_srcp,
                                                             const float* __restrict__ a_dstp,
                                                             const float* __restrict__ x,
                                                             const float* __restrict__ bias,
                                                             const float* __restrict__ gamma,
                                                             const float* __restrict__ beta,
                                                             float* __restrict__ out) {
    int node = blockIdx.x * 4 + (threadIdx.x >> 6);
    if (node >= N_NODES) return;
    const int lane = threadIdx.x & 63;
    const int q = lane >> 4;           // quarter 0..3
    const int ql = lane & 15;          // lane within quarter
    const int ch = ql * 8;             // 8 channels per lane
    const int head = ql >> 1;          // 2 lanes per head

    const float adst = a_dstp[node * 8 + head];

    const int beg = row_beg[node];
    const int end = row_end[node];

    float s = 0.f;
    float accv[8] = {};

    const char* __restrict__ hbase = reinterpret_cast<const char*>(h16);
    const unsigned chb = (unsigned)(ql * 16);   // byte offset of this lane's chunk

#define LOADH(dst_, sidx_) \
    dst_ = *reinterpret_cast<const uint4*>(hbase + ((unsigned)(sidx_) * 256u + chb))
#define LOADA(dst_, sidx_) dst_ = __half2float(a_srcp[(sidx_) * 8 + head])

#define CONSUME(hv_, av_)                                                  \
    {                                                                      \
        float e = (av_) + adst;                                            \
        e = fmaxf(e, NEG_SLOPE * e);                                       \
        e = fminf(e, 80.f);                                                \
        const float p = __expf(e);                                         \
        s += p;                                                            \
        const __half* hh = reinterpret_cast<const __half*>(&(hv_));        \
        _Pragma("unroll")                                                  \
        for (int j = 0; j < 8; ++j)                                        \
            accv[j] = fmaf(p, __half2float(hh[j]), accv[j]);               \
    }

#define REFILL(hv_, av_, iv_)                                              \
    {                                                                      \
        const int ic = inext < end ? inext : endm1;                        \
        const int sn = csr_src[ic];                                        \
        LOADH(hv_, sn);                                                    \
        LOADA(av_, sn);                                                    \
        iv_ = inext;                                                       \
        inext += 4;                                                        \
    }

    const int i0 = beg + q;
    if (i0 < end) {
        const int endm1 = end - 1;
        int iA = i0, iB = i0 + 4, iC = i0 + 8, iD = i0 + 12;
        const int cB = iB < end ? iB : endm1;
        const int cC = iC < end ? iC : endm1;
        const int cD = iD < end ? iD : endm1;
        const int sA = csr_src[iA];
        const int sB = csr_src[cB];
        const int sC = csr_src[cC];
        const int sD = csr_src[cD];
        uint4 hA, hB, hC, hD;
        float aA, aB, aC, aD;
        LOADH(hA, sA); LOADA(aA, sA);
        LOADH(hB, sB); LOADA(aB, sB);
        LOADH(hC, sC); LOADA(aC, sC);
        LOADH(hD, sD); LOADA(aD, sD);
        int inext = i0 + 16;
        for (;;) {
            CONSUME(hA, aA);
            REFILL(hA, aA, iA);
            if (iB >= end) break;
            CONSUME(hB, aB);
            REFILL(hB, aB, iB);
            if (iC >= end) break;
            CONSUME(hC, aC);
            REFILL(hC, aC, iC);
            if (iD >= end) break;
            CONSUME(hD, aD);
            REFILL(hD, aD, iD);
            if (iA >= end) break;
        }
    }
#undef LOADH
#undef LOADA
#undef CONSUME
#undef REFILL

    // combine the four quarters (each channel present in all quarters)
    s += __shfl_xor(s, 16);
    s += __shfl_xor(s, 32);
#pragma unroll
    for (int j = 0; j < 8; ++j) {
        accv[j] += __shfl_xor(accv[j], 16);
        accv[j] += __shfl_xor(accv[j], 32);
    }

    // normalize + bias + residual (x is touch-once: non-temporal)
    const float rs = 1.0f / (s + 1e-16f);
    const float* xrp = x + (size_t)node * 128 + ch;
    float v[8];
#pragma unroll
    for (int j = 0; j < 8; ++j) {
        const float xr = __builtin_nontemporal_load(xrp + j);
        v[j] = accv[j] * rs + bias[ch + j] + xr;
    }

    // LayerNorm over 128 channels (full-wave reduce; every channel counted 4x)
    float sum = 0.f, sq = 0.f;
#pragma unroll
    for (int j = 0; j < 8; ++j) {
        sum += v[j];
        sq = fmaf(v[j], v[j], sq);
    }
#pragma unroll
    for (int off = 32; off > 0; off >>= 1) {
        sum += __shfl_xor(sum, off);
        sq += __shfl_xor(sq, off);
    }
    const float mu = sum * (1.0f / 512.0f);
    const float var = sq * (1.0f / 512.0f) - mu * mu;
    const float inv = rsqrtf(var + LN_EPS);
    if (q == 0) {
        float o[8];
#pragma unroll
        for (int j = 0; j < 8; ++j) {
            float tt = (v[j] - mu) * inv * gamma[ch + j] + beta[ch + j];
            o[j] = tt > 0.f ? tt : 0.f;
        }
        float* op = out + (size_t)node * 128 + ch;
#pragma unroll
        for (int j = 0; j < 8; ++j) __builtin_nontemporal_store(o[j], op + j);
    }
}

extern "C" void kernel_launch(void* const* d_in, const int* in_sizes, int n_in,
                              void* d_out, int out_size, void* d_ws, size_t ws_size,
                              hipStream_t stream) {
    const float* x = (const float*)d_in[0];
    const int* ei = (const int*)d_in[1];
    const float* W = (const float*)d_in[2];
    const float* att_src = (const float*)d_in[3];
    const float* att_dst = (const float*)d_in[4];
    const float* bias = (const float*)d_in[5];
    const float* gamma = (const float*)d_in[6];
    const float* beta = (const float*)d_in[7];
    float* out = (float*)d_out;

    char* base = (char*)d_ws;
    __half* h16    = (__half*)base;                     // 25.6 MB
    __half* a_srcp = (__half*)(base + 25600000);        // 1.6 MB
    float* a_dstp  = (float*)(base + 27200000);         // 3.2 MB
    int* csr_src   = (int*)(base + 30400000);           // 12.81 MB (padded 782*4096*4)
    int* row_beg   = (int*)(base + 43212288);           // 400 KB
    int* row_end   = (int*)(base + 43612288);           // 400 KB
    unsigned* binned = (unsigned*)(base + 44012288);    // 12.81 MB (padded)
    int* bucket_cursor = (int*)(base + 56824576);       // 3,128 B

    hipMemsetAsync(bucket_cursor, 0, NB * sizeof(int), stream);
    gemm_bin_kernel<<<GEMM_BLOCKS + BIN_BLOCKS, 256, 0, stream>>>(
        x, W, att_src, att_dst, ei, h16, a_srcp, a_dstp, bucket_cursor, binned);
    csr_build_kernel<<<NB, 256, 0, stream>>>(binned, bucket_cursor, row_beg, row_end, csr_src);
    node_aggregate_kernel<<<(N_NODES + 3) / 4, 256, 0, stream>>>(
        row_beg, row_end, csr_src, h16, a_srcp, a_dstp, x, bias, gamma, beta, out);
}

// Round 9
// 147.410 us; speedup vs baseline: 2.8483x; 1.1090x over previous
//
#include <hip/hip_runtime.h>
#include <hip/hip_fp16.h>

#define N_NODES 100000
#define N_EDGES 1600000
#define NEG_SLOPE 0.2f
#define LN_EPS 1e-5f
#define NB 782            // ceil(N_NODES / 128) buckets, bucket = dst >> 7
#define GEMM_BLOCKS 782   // ceil(N_NODES / 128)
#define BIN_BLOCKS 196    // ceil(N_EDGES / 8192)
#define BIN_EDGES 8192
#define BUCKET_CAP 4096   // padded per-bucket capacity (mean 2048, sigma 45 -> safe)
#define CSR_CAP 2816      // LDS stage capacity per bucket (global fallback above)

typedef _Float16 f16x8 __attribute__((ext_vector_type(8)));
typedef float f32x4 __attribute__((ext_vector_type(4)));

#define XLDS_LD 136       // fp16 row stride for x_lds (128 + 8 pad -> bank spread)

// ---------------- fused MFMA-GEMM + direct-bin mega-kernel ----------------
// blocks [0, GEMM_BLOCKS): h16 = fp16(x @ W) via v_mfma_f32_16x16x32_f16,
//   fused a_src(fp16)/a_dst(fp32) epilogue computed from the LDS h copy.
// blocks [GEMM_BLOCKS, +BIN_BLOCKS): two-pass LDS bin of edges into PADDED
//   per-bucket regions binned[bucket*BUCKET_CAP + ...].
__global__ __launch_bounds__(256) void gemm_bin_kernel(const float* __restrict__ x,
                                                       const float* __restrict__ W,
                                                       const float* __restrict__ att_src,
                                                       const float* __restrict__ att_dst,
                                                       const int* __restrict__ ei,
                                                       __half* __restrict__ h16,
                                                       __half* __restrict__ a_srcp,
                                                       float* __restrict__ a_dstp,
                                                       int* __restrict__ bucket_cursor,
                                                       unsigned* __restrict__ binned) {
    // union LDS: GEMM uses x_lds (34,816 B) + w_frag (32,768 B); bin uses 2 int arrays
    __shared__ __align__(16) char lds[34816 + 32768];
    const int t = threadIdx.x;

    if (blockIdx.x >= GEMM_BLOCKS) {
        // ---------------- direct-bin branch ----------------
        int* hist = reinterpret_cast<int*>(lds);
        int* cbase = reinterpret_cast<int*>(lds + 4096);
        for (int i = t; i < NB; i += 256) hist[i] = 0;
        __syncthreads();
        const int e0 = (blockIdx.x - GEMM_BLOCKS) * BIN_EDGES;
        const int4* dsts = reinterpret_cast<const int4*>(ei + N_EDGES);
        const int b4 = e0 >> 2;
        for (int i = t; i < BIN_EDGES / 4; i += 256) {
            int idx = b4 + i;
            if (idx < N_EDGES / 4) {
                int4 d = dsts[idx];
                atomicAdd(&hist[d.x >> 7], 1);
                atomicAdd(&hist[d.y >> 7], 1);
                atomicAdd(&hist[d.z >> 7], 1);
                atomicAdd(&hist[d.w >> 7], 1);
            }
        }
        __syncthreads();
        for (int i = t; i < NB; i += 256) {
            int c = hist[i];
            cbase[i] = c ? atomicAdd(&bucket_cursor[i], c) : 0;
        }
        __syncthreads();
        for (int i = t; i < NB; i += 256) hist[i] = 0;   // reuse as local cursor
        __syncthreads();
        for (int i = t; i < BIN_EDGES; i += 256) {
            int e = e0 + i;
            if (e < N_EDGES) {
                int s_ = ei[e];
                int d = ei[N_EDGES + e];
                int bk = d >> 7;
                int off = atomicAdd(&hist[bk], 1);
                binned[bk * BUCKET_CAP + cbase[bk] + off] = (unsigned)((s_ << 7) | (d & 127));
            }
        }
        return;
    }

    // ---------------- MFMA GEMM branch ----------------
    _Float16* x_lds = reinterpret_cast<_Float16*>(lds);            // [128][XLDS_LD]
    _Float16* w_frag = reinterpret_cast<_Float16*>(lds + 34816);   // [4][8][64][8]
    const int nbase = blockIdx.x * 128;
    const int w = t >> 6;      // wave 0..3
    const int l = t & 63;
    const int lr = l & 15;     // A-row / B-col / D-col within tile
    const int lg = l >> 4;     // 16-lane group 0..3

    // stage x tile fp32 -> fp16 (coalesced float4 reads, 16B LDS writes)
    for (int i = t; i < 2048; i += 256) {
        int r = i >> 4, seg = i & 15;
        int gr = nbase + r;
        gr = gr < N_NODES ? gr : N_NODES - 1;
        const float4 v0 = *reinterpret_cast<const float4*>(&x[(size_t)gr * 128 + seg * 8]);
        const float4 v1 = *reinterpret_cast<const float4*>(&x[(size_t)gr * 128 + seg * 8 + 4]);
        _Float16 hb[8] = {(_Float16)v0.x, (_Float16)v0.y, (_Float16)v0.z, (_Float16)v0.w,
                          (_Float16)v1.x, (_Float16)v1.y, (_Float16)v1.z, (_Float16)v1.w};
        *reinterpret_cast<uint4*>(&x_lds[r * XLDS_LD + seg * 8]) =
            *reinterpret_cast<const uint4*>(hb);
    }
    // stage W into B-fragment order: w_frag[((ks*8+ct)*64+lane)*8 + j]
    //   = W[ks*32 + (lane>>4)*8 + j][ct*16 + (lane&15)]   (L2-hot strided reads)
    for (int s = t; s < 2048; s += 256) {
        int ks = s >> 9, ct = (s >> 6) & 7, ln = s & 63;
        int kb = ks * 32 + (ln >> 4) * 8;
        int col = ct * 16 + (ln & 15);
        _Float16 wb[8];
#pragma unroll
        for (int j = 0; j < 8; ++j) wb[j] = (_Float16)W[(size_t)(kb + j) * 128 + col];
        *reinterpret_cast<uint4*>(&w_frag[s * 8]) = *reinterpret_cast<const uint4*>(wb);
    }
    __syncthreads();

    f32x4 acc[2][8] = {};
    const int m0 = w * 32;
#pragma unroll
    for (int ks = 0; ks < 4; ++ks) {
        f16x8 a[2], b[8];
#pragma unroll
        for (int rt = 0; rt < 2; ++rt)
            a[rt] = *reinterpret_cast<const f16x8*>(
                &x_lds[(m0 + rt * 16 + lr) * XLDS_LD + ks * 32 + lg * 8]);
#pragma unroll
        for (int ct = 0; ct < 8; ++ct)
            b[ct] = *reinterpret_cast<const f16x8*>(&w_frag[((ks * 8 + ct) * 64 + l) * 8]);
#pragma unroll
        for (int rt = 0; rt < 2; ++rt)
#pragma unroll
            for (int ct = 0; ct < 8; ++ct)
                acc[rt][ct] = __builtin_amdgcn_mfma_f32_16x16x32_f16(a[rt], b[ct],
                                                                     acc[rt][ct], 0, 0, 0);
    }
    __syncthreads();   // done reading x_lds/w_frag; reuse x_lds for h output
    // D mapping (m89-verified): D[(lane>>4)*4 + reg][lane&15] per 16x16 tile
#pragma unroll
    for (int rt = 0; rt < 2; ++rt)
#pragma unroll
        for (int ct = 0; ct < 8; ++ct)
#pragma unroll
            for (int reg = 0; reg < 4; ++reg)
                x_lds[(m0 + rt * 16 + lg * 4 + reg) * XLDS_LD + ct * 16 + lr] =
                    (_Float16)acc[rt][ct][reg];
    __syncthreads();
    // coalesced h16 store
    for (int i = t; i < 2048; i += 256) {
        int r = i >> 4, seg = i & 15;
        int gr = nbase + r;
        if (gr < N_NODES)
            *reinterpret_cast<uint4*>(&h16[(size_t)gr * 128 + seg * 8]) =
                *reinterpret_cast<const uint4*>(&x_lds[r * XLDS_LD + seg * 8]);
    }
    // a_src / a_dst epilogue from the LDS h copy
    for (int idx = t; idx < 1024; idx += 256) {
        int row = idx >> 3, hd = idx & 7;
        int gr = nbase + row;
        if (gr < N_NODES) {
            float ps = 0.f, pd = 0.f;
#pragma unroll
            for (int j = 0; j < 16; ++j) {
                const float hv = (float)x_lds[row * XLDS_LD + hd * 16 + j];
                ps = fmaf(hv, att_src[hd * 16 + j], ps);
                pd = fmaf(hv, att_dst[hd * 16 + j], pd);
            }
            a_srcp[gr * 8 + hd] = __float2half_rn(ps);
            a_dstp[gr * 8 + hd] = pd;
        }
    }
}

// ---------------- build row_beg/row_end + csr_src (padded), one block/bucket ----
__global__ __launch_bounds__(256) void csr_build_kernel(const unsigned* __restrict__ binned,
                                                        const int* __restrict__ bucket_cursor,
                                                        int* __restrict__ row_beg,
                                                        int* __restrict__ row_end,
                                                        int* __restrict__ csr_src) {
    __shared__ int deg[128];
    __shared__ int sc[128];
    __shared__ int cur[128];
    __shared__ unsigned stage[CSR_CAP];
    const int b = blockIdx.x;
    const int t = threadIdx.x;
    const int pbase = b * BUCKET_CAP;
    const int cnt = bucket_cursor[b];
    const int n0 = b << 7;
    const bool fits = cnt <= CSR_CAP;
    if (t < 128) deg[t] = 0;
    __syncthreads();
    if (fits) {
        for (int i = t; i < cnt; i += 256) {
            unsigned p = binned[pbase + i];
            stage[i] = p;
            atomicAdd(&deg[p & 127], 1);
        }
    } else {
        for (int i = t; i < cnt; i += 256)
            atomicAdd(&deg[binned[pbase + i] & 127], 1);
    }
    __syncthreads();
    if (t < 128) sc[t] = deg[t];
    __syncthreads();
    for (int off = 1; off < 128; off <<= 1) {
        int u = (t < 128 && t >= off) ? sc[t - off] : 0;
        __syncthreads();
        if (t < 128) sc[t] += u;
        __syncthreads();
    }
    if (t < 128) {
        int excl = sc[t] - deg[t];
        cur[t] = excl;
        int n = n0 + t;
        if (n < N_NODES) {
            row_beg[n] = pbase + excl;
            row_end[n] = pbase + excl + deg[t];
        }
    }
    __syncthreads();
    if (fits) {
        for (int i = t; i < cnt; i += 256) {
            unsigned p = stage[i];
            int off = atomicAdd(&cur[p & 127], 1);
            csr_src[pbase + off] = (int)(p >> 7);
        }
    } else {
        for (int i = t; i < cnt; i += 256) {
            unsigned p = binned[pbase + i];
            int off = atomicAdd(&cur[p & 127], 1);
            csr_src[pbase + off] = (int)(p >> 7);
        }
    }
}

// ---------------- fused per-node aggregate + softmax + LN (unchanged R8) -------
__global__ __launch_bounds__(256) void node_aggregate_kernel(const int* __restrict__ row_beg,
                                                             const int* __restrict__ row_end,
                                                             const int* __restrict__ csr_src,
                                                             const __half* __restrict__ h16,
                                                             const __half* __restrict__ a_srcp,
                                                             const float* __restrict__ a_dstp,
                                                             const float* __restrict__ x,
                                                             const float* __restrict__ bias,
                                                             const float* __restrict__ gamma,
                                                             const float* __restrict__ beta,
                                                             float* __restrict__ out) {
    int node = blockIdx.x * 4 + (threadIdx.x >> 6);
    if (node >= N_NODES) return;
    const int lane = threadIdx.x & 63;
    const int q = lane >> 4;           // quarter 0..3
    const int ql = lane & 15;          // lane within quarter
    const int ch = ql * 8;             // 8 channels per lane
    const int head = ql >> 1;          // 2 lanes per head

    const float adst = a_dstp[node * 8 + head];

    const int beg = row_beg[node];
    const int end = row_end[node];

    float s = 0.f;
    float accv[8] = {};

    const char* __restrict__ hbase = reinterpret_cast<const char*>(h16);
    const unsigned chb = (unsigned)(ql * 16);   // byte offset of this lane's chunk

#define LOADH(dst_, sidx_) \
    dst_ = *reinterpret_cast<const uint4*>(hbase + ((unsigned)(sidx_) * 256u + chb))
#define LOADA(dst_, sidx_) dst_ = __half2float(a_srcp[(sidx_) * 8 + head])

#define CONSUME(hv_, av_)                                                  \
    {                                                                      \
        float e = (av_) + adst;                                            \
        e = fmaxf(e, NEG_SLOPE * e);                                       \
        e = fminf(e, 80.f);                                                \
        const float p = __expf(e);                                         \
        s += p;                                                            \
        const __half* hh = reinterpret_cast<const __half*>(&(hv_));        \
        _Pragma("unroll")                                                  \
        for (int j = 0; j < 8; ++j)                                        \
            accv[j] = fmaf(p, __half2float(hh[j]), accv[j]);               \
    }

#define REFILL(hv_, av_, iv_)                                              \
    {                                                                      \
        const int ic = inext < end ? inext : endm1;                        \
        const int sn = csr_src[ic];                                        \
        LOADH(hv_, sn);                                                    \
        LOADA(av_, sn);                                                    \
        iv_ = inext;                                                       \
        inext += 4;                                                        \
    }

    const int i0 = beg + q;
    if (i0 < end) {
        const int endm1 = end - 1;
        int iA = i0, iB = i0 + 4, iC = i0 + 8, iD = i0 + 12;
        const int cB = iB < end ? iB : endm1;
        const int cC = iC < end ? iC : endm1;
        const int cD = iD < end ? iD : endm1;
        const int sA = csr_src[iA];
        const int sB = csr_src[cB];
        const int sC = csr_src[cC];
        const int sD = csr_src[cD];
        uint4 hA, hB, hC, hD;
        float aA, aB, aC, aD;
        LOADH(hA, sA); LOADA(aA, sA);
        LOADH(hB, sB); LOADA(aB, sB);
        LOADH(hC, sC); LOADA(aC, sC);
        LOADH(hD, sD); LOADA(aD, sD);
        int inext = i0 + 16;
        for (;;) {
            CONSUME(hA, aA);
            REFILL(hA, aA, iA);
            if (iB >= end) break;
            CONSUME(hB, aB);
            REFILL(hB, aB, iB);
            if (iC >= end) break;
            CONSUME(hC, aC);
            REFILL(hC, aC, iC);
            if (iD >= end) break;
            CONSUME(hD, aD);
            REFILL(hD, aD, iD);
            if (iA >= end) break;
        }
    }
#undef LOADH
#undef LOADA
#undef CONSUME
#undef REFILL

    // combine the four quarters (each channel present in all quarters)
    s += __shfl_xor(s, 16);
    s += __shfl_xor(s, 32);
#pragma unroll
    for (int j = 0; j < 8; ++j) {
        accv[j] += __shfl_xor(accv[j], 16);
        accv[j] += __shfl_xor(accv[j], 32);
    }

    // normalize + bias + residual (x is touch-once: non-temporal)
    const float rs = 1.0f / (s + 1e-16f);
    const float* xrp = x + (size_t)node * 128 + ch;
    float v[8];
#pragma unroll
    for (int j = 0; j < 8; ++j) {
        const float xr = __builtin_nontemporal_load(xrp + j);
        v[j] = accv[j] * rs + bias[ch + j] + xr;
    }

    // LayerNorm over 128 channels (full-wave reduce; every channel counted 4x)
    float sum = 0.f, sq = 0.f;
#pragma unroll
    for (int j = 0; j < 8; ++j) {
        sum += v[j];
        sq = fmaf(v[j], v[j], sq);
    }
#pragma unroll
    for (int off = 32; off > 0; off >>= 1) {
        sum += __shfl_xor(sum, off);
        sq += __shfl_xor(sq, off);
    }
    const float mu = sum * (1.0f / 512.0f);
    const float var = sq * (1.0f / 512.0f) - mu * mu;
    const float inv = rsqrtf(var + LN_EPS);
    if (q == 0) {
        float o[8];
#pragma unroll
        for (int j = 0; j < 8; ++j) {
            float tt = (v[j] - mu) * inv * gamma[ch + j] + beta[ch + j];
            o[j] = tt > 0.f ? tt : 0.f;
        }
        float* op = out + (size_t)node * 128 + ch;
#pragma unroll
        for (int j = 0; j < 8; ++j) __builtin_nontemporal_store(o[j], op + j);
    }
}

extern "C" void kernel_launch(void* const* d_in, const int* in_sizes, int n_in,
                              void* d_out, int out_size, void* d_ws, size_t ws_size,
                              hipStream_t stream) {
    const float* x = (const float*)d_in[0];
    const int* ei = (const int*)d_in[1];
    const float* W = (const float*)d_in[2];
    const float* att_src = (const float*)d_in[3];
    const float* att_dst = (const float*)d_in[4];
    const float* bias = (const float*)d_in[5];
    const float* gamma = (const float*)d_in[6];
    const float* beta = (const float*)d_in[7];
    float* out = (float*)d_out;

    char* base = (char*)d_ws;
    __half* h16    = (__half*)base;                     // 25.6 MB
    __half* a_srcp = (__half*)(base + 25600000);        // 1.6 MB
    float* a_dstp  = (float*)(base + 27200000);         // 3.2 MB
    int* csr_src   = (int*)(base + 30400000);           // 12.81 MB (padded 782*4096*4)
    int* row_beg   = (int*)(base + 43212288);           // 400 KB
    int* row_end   = (int*)(base + 43612288);           // 400 KB
    unsigned* binned = (unsigned*)(base + 44012288);    // 12.81 MB (padded)
    int* bucket_cursor = (int*)(base + 56824576);       // 3,128 B

    hipMemsetAsync(bucket_cursor, 0, NB * sizeof(int), stream);
    gemm_bin_kernel<<<GEMM_BLOCKS + BIN_BLOCKS, 256, 0, stream>>>(
        x, W, att_src, att_dst, ei, h16, a_srcp, a_dstp, bucket_cursor, binned);
    csr_build_kernel<<<NB, 256, 0, stream>>>(binned, bucket_cursor, row_beg, row_end, csr_src);
    node_aggregate_kernel<<<(N_NODES + 3) / 4, 256, 0, stream>>>(
        row_beg, row_end, csr_src, h16, a_srcp, a_dstp, x, bias, gamma, beta, out);
}